// Round 8
// baseline (482.065 us; speedup 1.0000x reference)
//
#include <hip/hip_runtime.h>
#include <hip/hip_bf16.h>
#include <math.h>

// H=W=56, C=128, WS=7, SS=3, NH=4, P=5, HD=32, NW=64, NTOK=49, N=54, B=64
// x rows: 3141 = 5 + 56*56; window-rows: 4096 = B*NW; tokens/window: 54

typedef __attribute__((ext_vector_type(8))) short bf16x8;
typedef __attribute__((ext_vector_type(4))) float f32x4;
typedef __attribute__((ext_vector_type(4))) unsigned short u16x4;

__device__ __forceinline__ float bf2f(unsigned short u) {
  union { unsigned int i; float f; } v; v.i = ((unsigned)u) << 16; return v.f;
}
__device__ __forceinline__ unsigned short f2b(float f) {
  __hip_bfloat16 b = __float2bfloat16(f);
  return *reinterpret_cast<unsigned short*>(&b);
}

// ---------------------------------------------------------------------------
// Weight convert: wt[n][k] = bf16(w[k][n])
// ---------------------------------------------------------------------------
__global__ __launch_bounds__(256) void convert_wt(const float* __restrict__ w,
    __hip_bfloat16* __restrict__ wt, int K, int N)
{
  int idx = blockIdx.x * 256 + threadIdx.x;
  if (idx >= N * K) return;
  int n = idx / K, k = idx % K;
  wt[idx] = __float2bfloat16(w[(size_t)k * N + n]);
}

// ---------------------------------------------------------------------------
// Bias table gen (once): bias2[w][h][q][k] bf16, exp2-domain; k>=54 -> -inf
// ---------------------------------------------------------------------------
__global__ __launch_bounds__(256) void bias_gen(const float* __restrict__ rpb,
    __hip_bfloat16* __restrict__ tab)
{
  int w = blockIdx.x >> 2, h = blockIdx.x & 3;
  int wh = w >> 3, ww = w & 7;
  #pragma unroll
  for (int e = 0; e < 16; ++e) {
    int fi = e * 256 + threadIdx.x;
    int q = fi >> 6, k = fi & 63;
    float v;
    if (k >= 54) {
      v = -INFINITY;
    } else {
      v = 0.f;
      if (q >= 5 && q < 54 && k >= 5) {
        int tq = q - 5, tk = k - 5;
        int aq = tq / 7, bq_ = tq % 7, ak = tk / 7, bk = tk % 7;
        int dh = aq - ak + 6, dw = bq_ - bk + 6;
        v = rpb[(dh * 13 + dw) * 4 + h];
        int rq = wh * 7 + aq, cq = ww * 7 + bq_;
        int rk = wh * 7 + ak, ck = ww * 7 + bk;
        int zq = (rq < 49 ? 0 : (rq < 53 ? 1 : 2)) * 3 + (cq < 49 ? 0 : (cq < 53 ? 1 : 2));
        int zk = (rk < 49 ? 0 : (rk < 53 ? 1 : 2)) * 3 + (ck < 49 ? 0 : (ck < 53 ? 1 : 2));
        if (zq != zk) v += -100.f;
      }
      v *= 1.44269504088896f;
    }
    tab[((size_t)blockIdx.x << 12) + fi] = __float2bfloat16(v);
  }
}

// ---------------------------------------------------------------------------
// LN1 + window gather -> xw_c bf16
// ---------------------------------------------------------------------------
__global__ __launch_bounds__(256) void ln1_gather(const float* __restrict__ x,
    const float* __restrict__ g, const float* __restrict__ bta,
    __hip_bfloat16* __restrict__ xw, int i0, int nrows)
{
  int wid = blockIdx.x * 4 + (threadIdx.x >> 6);
  if (wid >= nrows) return;
  int lane = threadIdx.x & 63;
  int i = i0 + wid / 54, n = wid % 54;
  int src;
  if (n < 5) {
    src = (i & 63) * 3141 + n;
  } else {
    int b = i >> 6, w = i & 63;
    int t = n - 5;
    int hp = (w >> 3) * 7 + t / 7 + 3; if (hp >= 56) hp -= 56;
    int wp = (w & 7) * 7 + t % 7 + 3;  if (wp >= 56) wp -= 56;
    src = b * 3141 + 5 + hp * 56 + wp;
  }
  const float* xr = x + (size_t)src * 128;
  float v0 = xr[lane], v1 = xr[lane + 64];
  float s = v0 + v1, s2 = v0 * v0 + v1 * v1;
  #pragma unroll
  for (int off = 32; off > 0; off >>= 1) {
    s  += __shfl_xor(s,  off);
    s2 += __shfl_xor(s2, off);
  }
  float mu = s * (1.f / 128.f);
  float var = s2 * (1.f / 128.f) - mu * mu;
  float rs = rsqrtf(var + 1e-5f);
  __hip_bfloat16* o = xw + (size_t)wid * 128;
  o[lane]      = __float2bfloat16((v0 - mu) * rs * g[lane]      + bta[lane]);
  o[lane + 64] = __float2bfloat16((v1 - mu) * rs * g[lane + 64] + bta[lane + 64]);
}

// ---------------------------------------------------------------------------
// bf16 MFMA GEMM: C = A @ Wt^T + bias. A staged in LDS; W-frags read
// directly from global (L2-resident small weights).
// EPI 0: plain store (OUTBF selects bf16/f32). EPI 3: proj+scatter fused.
// ---------------------------------------------------------------------------
template<int EPI, int OUTBF>
__global__ __launch_bounds__(256) void gemm_mfma(
    const __hip_bfloat16* __restrict__ A, const __hip_bfloat16* __restrict__ Wt,
    const float* __restrict__ bias, void* __restrict__ Cout,
    const float* __restrict__ Rres, float* __restrict__ pbuf, int i0,
    int Mstore, int N, int K)
{
  __shared__ short As[8192];
  const int tid = threadIdx.x;
  const int wv = tid >> 6, lane = tid & 63;
  const int m0 = blockIdx.y * 128, n0 = blockIdx.x * 128;
  const int wr = wv >> 1, wc = wv & 1;
  const int c = lane & 15, g = lane >> 4;
  f32x4 acc[4][4] = {};
  const int srow = wv * 8 + (lane >> 3);
  const int schunk = lane & 7;

  for (int k0 = 0; k0 < K; k0 += 64) {
    #pragma unroll
    for (int i = 0; i < 4; ++i) {
      int row = i * 32 + srow;
      int kk = k0 + ((schunk ^ (row & 7)) << 3);
      const __hip_bfloat16* ga = A + (size_t)(m0 + row) * K + kk;
      __builtin_amdgcn_global_load_lds(
          (const __attribute__((address_space(1))) void*)ga,
          (__attribute__((address_space(3))) void*)(As + i * 2048 + wv * 512),
          16, 0, 0);
    }
    __syncthreads();
    #pragma unroll
    for (int s = 0; s < 2; ++s) {
      bf16x8 af[4], bfr[4];
      #pragma unroll
      for (int mi = 0; mi < 4; ++mi) {
        int r = wr * 64 + mi * 16 + c;
        int ch = ((s << 2) + g) ^ (r & 7);
        af[mi] = *(const bf16x8*)(As + r * 64 + ch * 8);
      }
      #pragma unroll
      for (int ni = 0; ni < 4; ++ni) {
        int r = n0 + wc * 64 + ni * 16 + c;
        bfr[ni] = *(const bf16x8*)(Wt + (size_t)r * K + k0 + s * 32 + g * 8);
      }
      #pragma unroll
      for (int mi = 0; mi < 4; ++mi)
        #pragma unroll
        for (int ni = 0; ni < 4; ++ni)
          acc[mi][ni] = __builtin_amdgcn_mfma_f32_16x16x32_bf16(
              af[mi], bfr[ni], acc[mi][ni], 0, 0, 0);
    }
    __syncthreads();
  }
  const int cl = c, rh = g;
  #pragma unroll
  for (int mi = 0; mi < 4; ++mi) {
    #pragma unroll
    for (int r = 0; r < 4; ++r) {
      int grow = m0 + wr * 64 + mi * 16 + rh * 4 + r;
      if (grow < Mstore) {
        if (EPI == 3) {
          int li = grow / 54, n = grow - li * 54;
          int gi = i0 + li;
          if (n < 5) {
            #pragma unroll
            for (int ni = 0; ni < 4; ++ni) {
              int gcol = n0 + wc * 64 + ni * 16 + cl;
              pbuf[((size_t)gi * 5 + n) * 128 + gcol] = acc[mi][ni][r] + bias[gcol];
            }
          } else {
            int b = gi >> 6, w = gi & 63, tt = n - 5;
            int rr = (w >> 3) * 7 + tt / 7 + 3; if (rr >= 56) rr -= 56;
            int cc = (w & 7) * 7 + tt % 7 + 3;  if (cc >= 56) cc -= 56;
            size_t ob = ((size_t)b * 3141 + 5 + rr * 56 + cc) * 128;
            #pragma unroll
            for (int ni = 0; ni < 4; ++ni) {
              int gcol = n0 + wc * 64 + ni * 16 + cl;
              ((float*)Cout)[ob + gcol] = Rres[ob + gcol] + acc[mi][ni][r] + bias[gcol];
            }
          }
        } else {
          #pragma unroll
          for (int ni = 0; ni < 4; ++ni) {
            int gcol = n0 + wc * 64 + ni * 16 + cl;
            float t = acc[mi][ni][r] + bias[gcol];
            if (OUTBF)
              ((__hip_bfloat16*)Cout)[(size_t)grow * N + gcol] = __float2bfloat16(t);
            else
              ((float*)Cout)[(size_t)grow * N + gcol] = t;
          }
        }
      }
    }
  }
}

// ---------------------------------------------------------------------------
// MFMA attention: block = window-row, wave = head. Barrier-free.
// ---------------------------------------------------------------------------
__global__ __launch_bounds__(256) void attn_mfma(
    const __hip_bfloat16* __restrict__ qkv,
    const __hip_bfloat16* __restrict__ bias_tab,
    __hip_bfloat16* __restrict__ attn_out, int i0)
{
  __shared__ short lds[24576];
  const int tid = threadIdx.x;
  const int h = tid >> 6, lane = tid & 63;
  const int li = blockIdx.x;
  const int w = (i0 + li) & 63;
  const int c = lane & 15, g = lane >> 4;
  short* Lh = lds + h * 6144;
  const unsigned short* qk = (const unsigned short*)qkv;

  #pragma unroll
  for (int m = 0; m < 3; ++m) {
    #pragma unroll
    for (int t = 0; t < 4; ++t) {
      int tok = t * 16 + (lane >> 2);
      int swz = (m == 2) ? ((tok >> 3) & 3) : ((tok >> 1) & 3);
      int ch = (lane & 3) ^ swz;
      const unsigned short* ga = qk + (size_t)(li * 54 + tok) * 384 + m * 128 + h * 32 + ch * 8;
      __builtin_amdgcn_global_load_lds(
          (const __attribute__((address_space(1))) void*)ga,
          (__attribute__((address_space(3))) void*)(Lh + m * 2048 + t * 512),
          16, 0, 0);
    }
  }

  const unsigned short* bt = (const unsigned short*)bias_tab + ((size_t)(w * 4 + h) << 12);
  u16x4 bb[4][4];
  #pragma unroll
  for (int ni = 0; ni < 4; ++ni)
    #pragma unroll
    for (int mi = 0; mi < 4; ++mi)
      bb[ni][mi] = *(const u16x4*)(bt + (ni * 16 + c) * 64 + mi * 16 + g * 4);

  asm volatile("s_waitcnt vmcnt(0)" ::: "memory");
  __builtin_amdgcn_sched_barrier(0);

  bf16x8 af[4], bq[4];
  #pragma unroll
  for (int mi = 0; mi < 4; ++mi) {
    int tok = mi * 16 + c;
    af[mi] = *(const bf16x8*)(Lh + 2048 + tok * 32 + ((g ^ ((tok >> 1) & 3)) << 3));
  }
  #pragma unroll
  for (int ni = 0; ni < 4; ++ni) {
    int q = ni * 16 + c;
    bq[ni] = *(const bf16x8*)(Lh + q * 32 + ((g ^ ((q >> 1) & 3)) << 3));
  }
  f32x4 acc[4][4] = {};
  #pragma unroll
  for (int mi = 0; mi < 4; ++mi)
    #pragma unroll
    for (int ni = 0; ni < 4; ++ni)
      acc[mi][ni] = __builtin_amdgcn_mfma_f32_16x16x32_bf16(af[mi], bq[ni], acc[mi][ni], 0, 0, 0);

  const float SC = 0.17677669529663689f * 1.44269504088896f;
  #pragma unroll
  for (int ni = 0; ni < 4; ++ni)
    #pragma unroll
    for (int mi = 0; mi < 4; ++mi)
      #pragma unroll
      for (int r = 0; r < 4; ++r)
        acc[mi][ni][r] = acc[mi][ni][r] * SC + bf2f(bb[ni][mi][r]);

  #pragma unroll
  for (int ni = 0; ni < 4; ++ni) {
    float m2 = -3.0e38f;
    #pragma unroll
    for (int mi = 0; mi < 4; ++mi)
      #pragma unroll
      for (int r = 0; r < 4; ++r)
        m2 = fmaxf(m2, acc[mi][ni][r]);
    m2 = fmaxf(m2, __shfl_xor(m2, 16, 64));
    m2 = fmaxf(m2, __shfl_xor(m2, 32, 64));
    float sm = 0.f;
    #pragma unroll
    for (int mi = 0; mi < 4; ++mi)
      #pragma unroll
      for (int r = 0; r < 4; ++r) {
        float p = exp2f(acc[mi][ni][r] - m2);
        acc[mi][ni][r] = p;
        sm += p;
      }
    sm += __shfl_xor(sm, 16, 64);
    sm += __shfl_xor(sm, 32, 64);
    float inv = 1.0f / sm;
    int q = ni * 16 + c;
    #pragma unroll
    for (int mi = 0; mi < 4; ++mi) {
      u16x4 pw;
      #pragma unroll
      for (int r = 0; r < 4; ++r) pw[r] = f2b(acc[mi][ni][r] * inv);
      int chp = (mi * 2 + (g >> 1)) ^ (q & 7);
      *(u16x4*)(Lh + q * 64 + chp * 8 + (g & 1) * 4) = pw;
    }
  }

  f32x4 acc2[4][2] = {};
  #pragma unroll
  for (int ks = 0; ks < 2; ++ks) {
    bf16x8 pa[4];
    #pragma unroll
    for (int qi = 0; qi < 4; ++qi) {
      int q = qi * 16 + c;
      int chk = (ks * 4 + g) ^ (q & 7);
      pa[qi] = *(const bf16x8*)(Lh + q * 64 + chk * 8);
    }
    bf16x8 vb[2];
    #pragma unroll
    for (int di = 0; di < 2; ++di) {
      #pragma unroll
      for (int j = 0; j < 8; ++j) {
        int k = ks * 32 + g * 8 + j;
        int chv = ((di * 2 + (c >> 3)) ^ g);
        vb[di][j] = Lh[4096 + k * 32 + chv * 8 + (c & 7)];
      }
    }
    #pragma unroll
    for (int qi = 0; qi < 4; ++qi)
      #pragma unroll
      for (int di = 0; di < 2; ++di)
        acc2[qi][di] = __builtin_amdgcn_mfma_f32_16x16x32_bf16(pa[qi], vb[di], acc2[qi][di], 0, 0, 0);
  }

  #pragma unroll
  for (int qi = 0; qi < 4; ++qi) {
    #pragma unroll
    for (int r = 0; r < 4; ++r) {
      int q = qi * 16 + g * 4 + r;
      if (q < 54) {
        __hip_bfloat16* orow = attn_out + (size_t)(li * 54 + q) * 128 + h * 32;
        #pragma unroll
        for (int di = 0; di < 2; ++di)
          orow[di * 16 + c] = __float2bfloat16(acc2[qi][di][r]);
      }
    }
  }
}

// ---------------------------------------------------------------------------
// Prompt mean over windows + residual
// ---------------------------------------------------------------------------
__global__ __launch_bounds__(128) void prompt_reduce(const float* __restrict__ x,
    const float* __restrict__ pbuf, float* __restrict__ out)
{
  int bp = blockIdx.x;
  int b = bp / 5, p = bp % 5;
  int c = threadIdx.x;
  float s = 0.f;
  for (int w = 0; w < 64; ++w)
    s += pbuf[((size_t)(w * 64 + b) * 5 + p) * 128 + c];
  size_t oidx = ((size_t)b * 3141 + p) * 128 + c;
  out[oidx] = x[oidx] + s * (1.f / 64.f);
}

// ---------------------------------------------------------------------------
// MLP helpers: fc1(strip) -> GELU -> h buffer; fc2(strip) accumulate.
// ---------------------------------------------------------------------------
__device__ __forceinline__ void mlp_fc1(const short* __restrict__ xn,
    short* __restrict__ dst, const __hip_bfloat16* __restrict__ w1t,
    const float* __restrict__ b1, int s, int wv, int c, int g)
{
  bf16x8 wf[4][2];
  #pragma unroll
  for (int ks = 0; ks < 4; ++ks)
    #pragma unroll
    for (int ni = 0; ni < 2; ++ni)
      wf[ks][ni] = *(const bf16x8*)(w1t +
          (size_t)(s * 128 + wv * 32 + ni * 16 + c) * 128 + ks * 32 + g * 8);
  f32x4 acc1[4][2] = {};
  #pragma unroll
  for (int ks = 0; ks < 4; ++ks) {
    bf16x8 af[4];
    #pragma unroll
    for (int mi = 0; mi < 4; ++mi) {
      int row = mi * 16 + c;
      af[mi] = *(const bf16x8*)(xn + row * 128 +
                                (((ks * 4 + g) ^ ((row & 15) >> 1)) << 3));
    }
    #pragma unroll
    for (int mi = 0; mi < 4; ++mi)
      #pragma unroll
      for (int ni = 0; ni < 2; ++ni)
        acc1[mi][ni] = __builtin_amdgcn_mfma_f32_16x16x32_bf16(
            af[mi], wf[ks][ni], acc1[mi][ni], 0, 0, 0);
  }
  #pragma unroll
  for (int ni = 0; ni < 2; ++ni) {
    int col = wv * 32 + ni * 16 + c;
    float bv = b1[s * 128 + col];
    #pragma unroll
    for (int mi = 0; mi < 4; ++mi) {
      #pragma unroll
      for (int r = 0; r < 4; ++r) {
        int row = mi * 16 + g * 4 + r;
        float t = acc1[mi][ni][r] + bv;
        float u = t * (0.7978845608028654f + 0.0356774081f * t * t);
        float e = exp2f(-2.8853900817779268f * u);
        t = t * __builtin_amdgcn_rcpf(1.0f + e);
        dst[row * 128 + (((col >> 3) ^ ((row & 15) >> 1)) << 3) + (col & 7)] =
            (short)f2b(t);
      }
    }
  }
}

__device__ __forceinline__ void mlp_fc2(const short* __restrict__ hsrc,
    const __hip_bfloat16* __restrict__ w2t, f32x4 (&acc2)[4][2],
    int s, int wv, int c, int g)
{
  bf16x8 wf[4][2];
  #pragma unroll
  for (int ks = 0; ks < 4; ++ks)
    #pragma unroll
    for (int ni = 0; ni < 2; ++ni)
      wf[ks][ni] = *(const bf16x8*)(w2t +
          (size_t)(wv * 32 + ni * 16 + c) * 512 + s * 128 + ks * 32 + g * 8);
  #pragma unroll
  for (int ks = 0; ks < 4; ++ks) {
    bf16x8 af[4];
    #pragma unroll
    for (int mi = 0; mi < 4; ++mi) {
      int row = mi * 16 + c;
      af[mi] = *(const bf16x8*)(hsrc + row * 128 +
                                (((ks * 4 + g) ^ ((row & 15) >> 1)) << 3));
    }
    #pragma unroll
    for (int mi = 0; mi < 4; ++mi)
      #pragma unroll
      for (int ni = 0; ni < 2; ++ni)
        acc2[mi][ni] = __builtin_amdgcn_mfma_f32_16x16x32_bf16(
            af[mi], wf[ks][ni], acc2[mi][ni], 0, 0, 0);
  }
}

// ---------------------------------------------------------------------------
// Fused MLP v3: software-pipelined strips. Double-buffered h; ONE barrier
// per strip; fc1(s+1) and fc2(s) are independent streams between barriers
// (fc2 MFMA/loads overlap fc1's GELU VALU chain). LDS 48 KB -> 3 blocks/CU.
// ---------------------------------------------------------------------------
__global__ __launch_bounds__(256, 3) void mlp_fused(
    const float* __restrict__ xin,
    const float* __restrict__ gamma, const float* __restrict__ beta,
    const __hip_bfloat16* __restrict__ w1t, const float* __restrict__ b1,
    const __hip_bfloat16* __restrict__ w2t, const float* __restrict__ b2,
    float* __restrict__ outp)
{
  __shared__ short xn[8192];      // [64][128] bf16, chunk ^ ((row&15)>>1)
  __shared__ short hb[2][8192];   // double-buffered h
  const int tid = threadIdx.x;
  const int wv = tid >> 6, lane = tid & 63;
  const int c = lane & 15, g = lane >> 4;
  const int r0 = blockIdx.x * 64;

  // ---- LN2: wave wv handles rows wv*16..+15
  for (int rr = 0; rr < 16; ++rr) {
    int row = wv * 16 + rr;
    const float* xr = xin + (size_t)(r0 + row) * 128;
    float v0 = xr[lane], v1 = xr[lane + 64];
    float s = v0 + v1, s2 = v0 * v0 + v1 * v1;
    #pragma unroll
    for (int off = 32; off > 0; off >>= 1) {
      s  += __shfl_xor(s,  off);
      s2 += __shfl_xor(s2, off);
    }
    float mu = s * (1.f / 128.f);
    float var = s2 * (1.f / 128.f) - mu * mu;
    float rs = rsqrtf(var + 1e-5f);
    float y0 = (v0 - mu) * rs * gamma[lane]      + beta[lane];
    float y1 = (v1 - mu) * rs * gamma[lane + 64] + beta[lane + 64];
    int f = (row & 15) >> 1;
    int ca = lane, cb = lane + 64;
    xn[row * 128 + (((ca >> 3) ^ f) << 3) + (ca & 7)] = (short)f2b(y0);
    xn[row * 128 + (((cb >> 3) ^ f) << 3) + (cb & 7)] = (short)f2b(y1);
  }
  __syncthreads();

  // ---- prologue: fc1 strip 0 -> hb[0]
  mlp_fc1(xn, hb[0], w1t, b1, 0, wv, c, g);
  __syncthreads();

  // ---- pipelined strips: fc1(s+1) || fc2(s), one barrier per strip
  f32x4 acc2[4][2] = {};
  #pragma unroll
  for (int s = 0; s < 4; ++s) {
    if (s < 3) mlp_fc1(xn, hb[(s + 1) & 1], w1t, b1, s + 1, wv, c, g);
    mlp_fc2(hb[s & 1], w2t, acc2, s, wv, c, g);
    if (s < 3) __syncthreads();
  }

  // ---- epilogue: out = acc2 + b2 + x
  #pragma unroll
  for (int mi = 0; mi < 4; ++mi) {
    #pragma unroll
    for (int r = 0; r < 4; ++r) {
      int row = r0 + mi * 16 + g * 4 + r;
      #pragma unroll
      for (int ni = 0; ni < 2; ++ni) {
        int col = wv * 32 + ni * 16 + c;
        size_t o = (size_t)row * 128 + col;
        outp[o] = acc2[mi][ni][r] + b2[col] + xin[o];
      }
    }
  }
}

// ---------------------------------------------------------------------------
// Launch
// ---------------------------------------------------------------------------
extern "C" void kernel_launch(void* const* d_in, const int* in_sizes, int n_in,
                              void* d_out, int out_size, void* d_ws, size_t ws_size,
                              hipStream_t stream) {
  const float* x      = (const float*)d_in[0];
  const float* n1g    = (const float*)d_in[1];
  const float* n1b    = (const float*)d_in[2];
  const float* qkv_w  = (const float*)d_in[3];
  const float* qkv_b  = (const float*)d_in[4];
  const float* proj_w = (const float*)d_in[5];
  const float* proj_b = (const float*)d_in[6];
  const float* rpb    = (const float*)d_in[7];
  const float* n2g    = (const float*)d_in[8];
  const float* n2b    = (const float*)d_in[9];
  const float* fc1w   = (const float*)d_in[10];
  const float* fc1b   = (const float*)d_in[11];
  const float* fc2w   = (const float*)d_in[12];
  const float* fc2b   = (const float*)d_in[13];
  float* out = (float*)d_out;
  char* ws = (char*)d_ws;

  __hip_bfloat16* wbuf = (__hip_bfloat16*)ws;
  __hip_bfloat16* w_qkv = wbuf;
  __hip_bfloat16* w_prj = wbuf + 49152;
  __hip_bfloat16* w_fc1 = wbuf + 65536;
  __hip_bfloat16* w_fc2 = wbuf + 131072;
  __hip_bfloat16* bias_tab = (__hip_bfloat16*)(ws + 393216);
  float* pbuf = (float*)(ws + 2490368);
  const size_t CHUNK_BASE = 12976128ULL;

  hipLaunchKernelGGL(convert_wt, dim3(192), dim3(256), 0, stream, qkv_w, w_qkv, 128, 384);
  hipLaunchKernelGGL(convert_wt, dim3(64),  dim3(256), 0, stream, proj_w, w_prj, 128, 128);
  hipLaunchKernelGGL(convert_wt, dim3(256), dim3(256), 0, stream, fc1w,  w_fc1, 128, 512);
  hipLaunchKernelGGL(convert_wt, dim3(256), dim3(256), 0, stream, fc2w,  w_fc2, 512, 128);
  hipLaunchKernelGGL(bias_gen, dim3(256), dim3(256), 0, stream, rpb, bias_tab);

  // ---- Phase 1: LN1 -> QKV -> attn(MFMA) -> proj(+scatter fused)
  int cw = 2048;
  while (cw > 64 && CHUNK_BASE + (size_t)cw * 54 * 1024 + 8192 > ws_size) cw >>= 1;
  {
    size_t R = (size_t)cw * 54;
    __hip_bfloat16* xw_c  = (__hip_bfloat16*)(ws + CHUNK_BASE);
    __hip_bfloat16* qkv_c = (__hip_bfloat16*)(ws + CHUNK_BASE + R * 256);
    for (int i0 = 0; i0 < 4096; i0 += cw) {
      int nr = cw * 54;
      hipLaunchKernelGGL(ln1_gather, dim3((nr + 3) / 4), dim3(256), 0, stream,
                         x, n1g, n1b, xw_c, i0, nr);
      hipLaunchKernelGGL((gemm_mfma<0, 1>), dim3(3, nr / 128), dim3(256), 0, stream,
                         xw_c, w_qkv, qkv_b, qkv_c, (const float*)nullptr,
                         (float*)nullptr, 0, nr, 384, 128);
      hipLaunchKernelGGL(attn_mfma, dim3(cw), dim3(256), 0, stream,
                         qkv_c, bias_tab, xw_c, i0);
      hipLaunchKernelGGL((gemm_mfma<3, 0>), dim3(1, nr / 128), dim3(256), 0, stream,
                         xw_c, w_prj, proj_b, (void*)out, x, pbuf, i0, nr, 128, 128);
    }
    hipLaunchKernelGGL(prompt_reduce, dim3(320), dim3(128), 0, stream, x, pbuf, out);
  }

  // ---- Phase 2: fused MLP (in-place on out), 201024 = 3141*64 rows
  hipLaunchKernelGGL(mlp_fused, dim3(3141), dim3(256), 0, stream,
                     out, n2g, n2b, w_fc1, fc1b, w_fc2, fc2b, out);
  (void)in_sizes; (void)n_in; (void)out_size; (void)ws_size;
}

// Round 9
// 383.167 us; speedup vs baseline: 1.2581x; 1.2581x over previous
//
#include <hip/hip_runtime.h>
#include <hip/hip_bf16.h>
#include <math.h>

// H=W=56, C=128, WS=7, SS=3, NH=4, P=5, HD=32, NW=64, NTOK=49, N=54, B=64
// x rows: 3141 = 5 + 56*56; window-rows: 4096 = B*NW; tokens/window: 54

typedef __attribute__((ext_vector_type(8))) short bf16x8;
typedef __attribute__((ext_vector_type(4))) float f32x4;
typedef __attribute__((ext_vector_type(4))) unsigned short u16x4;

__device__ __forceinline__ float bf2f(unsigned short u) {
  union { unsigned int i; float f; } v; v.i = ((unsigned)u) << 16; return v.f;
}
__device__ __forceinline__ unsigned short f2b(float f) {
  __hip_bfloat16 b = __float2bfloat16(f);
  return *reinterpret_cast<unsigned short*>(&b);
}

// ---------------------------------------------------------------------------
// Weight convert: wt[n][k] = bf16(w[k][n])
// ---------------------------------------------------------------------------
__global__ __launch_bounds__(256) void convert_wt(const float* __restrict__ w,
    __hip_bfloat16* __restrict__ wt, int K, int N)
{
  int idx = blockIdx.x * 256 + threadIdx.x;
  if (idx >= N * K) return;
  int n = idx / K, k = idx % K;
  wt[idx] = __float2bfloat16(w[(size_t)k * N + n]);
}

// ---------------------------------------------------------------------------
// Bias table gen (once): bias2[w][h][q][k] bf16, exp2-domain; k>=54 -> -inf
// ---------------------------------------------------------------------------
__global__ __launch_bounds__(256) void bias_gen(const float* __restrict__ rpb,
    __hip_bfloat16* __restrict__ tab)
{
  int w = blockIdx.x >> 2, h = blockIdx.x & 3;
  int wh = w >> 3, ww = w & 7;
  #pragma unroll
  for (int e = 0; e < 16; ++e) {
    int fi = e * 256 + threadIdx.x;
    int q = fi >> 6, k = fi & 63;
    float v;
    if (k >= 54) {
      v = -INFINITY;
    } else {
      v = 0.f;
      if (q >= 5 && q < 54 && k >= 5) {
        int tq = q - 5, tk = k - 5;
        int aq = tq / 7, bq_ = tq % 7, ak = tk / 7, bk = tk % 7;
        int dh = aq - ak + 6, dw = bq_ - bk + 6;
        v = rpb[(dh * 13 + dw) * 4 + h];
        int rq = wh * 7 + aq, cq = ww * 7 + bq_;
        int rk = wh * 7 + ak, ck = ww * 7 + bk;
        int zq = (rq < 49 ? 0 : (rq < 53 ? 1 : 2)) * 3 + (cq < 49 ? 0 : (cq < 53 ? 1 : 2));
        int zk = (rk < 49 ? 0 : (rk < 53 ? 1 : 2)) * 3 + (ck < 49 ? 0 : (ck < 53 ? 1 : 2));
        if (zq != zk) v += -100.f;
      }
      v *= 1.44269504088896f;
    }
    tab[((size_t)blockIdx.x << 12) + fi] = __float2bfloat16(v);
  }
}

// ---------------------------------------------------------------------------
// Phase-1 mega-kernel: one block per window-row gi. 4 waves.
// LN1+gather -> xn(LDS) -> QKV MFMA (out straight into attn-layout LDS)
// -> attention (wave = head) -> ao(LDS, overlays xn) -> proj MFMA
// -> scatter/residual epilogue (spatial -> out, prompt -> pbuf).
// LDS 64KB: xn/ao [64][128] @0 (8192 shorts), QL @8192: head h at h*6144
// shorts {Q@0, K@2048, V@4096}; Ps overlays Q+K of own head.
// ---------------------------------------------------------------------------
__global__ __launch_bounds__(256, 2) void phase1_fused(
    const float* __restrict__ x,
    const float* __restrict__ n1g, const float* __restrict__ n1b,
    const __hip_bfloat16* __restrict__ w_qkv, const float* __restrict__ qkv_b,
    const __hip_bfloat16* __restrict__ w_prj, const float* __restrict__ proj_b,
    const __hip_bfloat16* __restrict__ bias_tab,
    float* __restrict__ out, float* __restrict__ pbuf)
{
  __shared__ short lds[32768];
  short* xn = lds;           // [64][128], chunk ^ ((row&15)>>1); later ao
  short* QL = lds + 8192;
  const int tid = threadIdx.x;
  const int wv = tid >> 6, lane = tid & 63;
  const int c = lane & 15, g = lane >> 4;
  const int gi = blockIdx.x;
  const int w = gi & 63;

  // ================= LN1 + window gather =================
  for (int rr = 0; rr < 16; ++rr) {
    int row = wv * 16 + rr;
    if (row >= 54) break;
    int src;
    if (row < 5) {
      src = (gi & 63) * 3141 + row;
    } else {
      int b = gi >> 6, t = row - 5;
      int hp = (w >> 3) * 7 + t / 7 + 3; if (hp >= 56) hp -= 56;
      int wp = (w & 7) * 7 + t % 7 + 3;  if (wp >= 56) wp -= 56;
      src = b * 3141 + 5 + hp * 56 + wp;
    }
    const float* xr = x + (size_t)src * 128;
    float v0 = xr[lane], v1 = xr[lane + 64];
    float s = v0 + v1, s2 = v0 * v0 + v1 * v1;
    #pragma unroll
    for (int off = 32; off > 0; off >>= 1) {
      s  += __shfl_xor(s,  off);
      s2 += __shfl_xor(s2, off);
    }
    float mu = s * (1.f / 128.f);
    float var = s2 * (1.f / 128.f) - mu * mu;
    float rs = rsqrtf(var + 1e-5f);
    float y0 = (v0 - mu) * rs * n1g[lane]      + n1b[lane];
    float y1 = (v1 - mu) * rs * n1g[lane + 64] + n1b[lane + 64];
    int f = (row & 15) >> 1;
    int ca = lane, cb = lane + 64;
    xn[row * 128 + (((ca >> 3) ^ f) << 3) + (ca & 7)] = (short)f2b(y0);
    xn[row * 128 + (((cb >> 3) ^ f) << 3) + (cb & 7)] = (short)f2b(y1);
  }
  // zero pad rows 54..63 (masked later by -inf bias / unstored rows)
  for (int idx = tid; idx < 1280; idx += 256) xn[54 * 128 + idx] = 0;
  __syncthreads();

  // ================= QKV GEMM into attn-layout LDS =================
  {
    bf16x8 af[4][4];
    #pragma unroll
    for (int ks = 0; ks < 4; ++ks)
      #pragma unroll
      for (int mi = 0; mi < 4; ++mi) {
        int row = mi * 16 + c;
        af[ks][mi] = *(const bf16x8*)(xn + row * 128 +
                      (((ks * 4 + g) ^ ((row & 15) >> 1)) << 3));
      }
    #pragma unroll
    for (int t = 0; t < 6; ++t) {
      int n0 = wv * 96 + t * 16;
      int m = n0 >> 7, rem = n0 & 127, hh = rem >> 5, chb = rem & 31;
      bf16x8 bfr[4];
      #pragma unroll
      for (int ks = 0; ks < 4; ++ks)
        bfr[ks] = *(const bf16x8*)(w_qkv + (size_t)(n0 + c) * 128 + ks * 32 + g * 8);
      f32x4 acct[4] = {};
      #pragma unroll
      for (int ks = 0; ks < 4; ++ks)
        #pragma unroll
        for (int mi = 0; mi < 4; ++mi)
          acct[mi] = __builtin_amdgcn_mfma_f32_16x16x32_bf16(
              af[ks][mi], bfr[ks], acct[mi], 0, 0, 0);
      float bq = qkv_b[n0 + c];
      int cpart = (chb >> 3) + (c >> 3);
      int e = c & 7;
      int base = hh * 6144 + m * 2048;
      #pragma unroll
      for (int mi = 0; mi < 4; ++mi) {
        #pragma unroll
        for (int r = 0; r < 4; ++r) {
          int tok = mi * 16 + g * 4 + r;
          int swz = (m == 2) ? ((tok >> 3) & 3) : ((tok >> 1) & 3);
          QL[base + tok * 32 + ((cpart ^ swz) << 3) + e] =
              (short)f2b(acct[mi][r] + bq);
        }
      }
    }
  }
  __syncthreads();

  // ================= attention (wave wv = head h) =================
  {
    const int h = wv;
    short* Lh = QL + h * 6144;
    const unsigned short* bt = (const unsigned short*)bias_tab + ((size_t)(w * 4 + h) << 12);
    u16x4 bb[4][4];
    #pragma unroll
    for (int ni = 0; ni < 4; ++ni)
      #pragma unroll
      for (int mi = 0; mi < 4; ++mi)
        bb[ni][mi] = *(const u16x4*)(bt + (ni * 16 + c) * 64 + mi * 16 + g * 4);

    bf16x8 af[4], bq[4];
    #pragma unroll
    for (int mi = 0; mi < 4; ++mi) {
      int tok = mi * 16 + c;
      af[mi] = *(const bf16x8*)(Lh + 2048 + tok * 32 + ((g ^ ((tok >> 1) & 3)) << 3));
    }
    #pragma unroll
    for (int ni = 0; ni < 4; ++ni) {
      int q = ni * 16 + c;
      bq[ni] = *(const bf16x8*)(Lh + q * 32 + ((g ^ ((q >> 1) & 3)) << 3));
    }
    f32x4 acc[4][4] = {};
    #pragma unroll
    for (int mi = 0; mi < 4; ++mi)
      #pragma unroll
      for (int ni = 0; ni < 4; ++ni)
        acc[mi][ni] = __builtin_amdgcn_mfma_f32_16x16x32_bf16(af[mi], bq[ni], acc[mi][ni], 0, 0, 0);

    const float SC = 0.17677669529663689f * 1.44269504088896f;
    #pragma unroll
    for (int ni = 0; ni < 4; ++ni)
      #pragma unroll
      for (int mi = 0; mi < 4; ++mi)
        #pragma unroll
        for (int r = 0; r < 4; ++r)
          acc[mi][ni][r] = acc[mi][ni][r] * SC + bf2f(bb[ni][mi][r]);

    #pragma unroll
    for (int ni = 0; ni < 4; ++ni) {
      float m2 = -3.0e38f;
      #pragma unroll
      for (int mi = 0; mi < 4; ++mi)
        #pragma unroll
        for (int r = 0; r < 4; ++r)
          m2 = fmaxf(m2, acc[mi][ni][r]);
      m2 = fmaxf(m2, __shfl_xor(m2, 16, 64));
      m2 = fmaxf(m2, __shfl_xor(m2, 32, 64));
      float sm = 0.f;
      #pragma unroll
      for (int mi = 0; mi < 4; ++mi)
        #pragma unroll
        for (int r = 0; r < 4; ++r) {
          float p = exp2f(acc[mi][ni][r] - m2);
          acc[mi][ni][r] = p;
          sm += p;
        }
      sm += __shfl_xor(sm, 16, 64);
      sm += __shfl_xor(sm, 32, 64);
      float inv = 1.0f / sm;
      int q = ni * 16 + c;
      #pragma unroll
      for (int mi = 0; mi < 4; ++mi) {
        u16x4 pw;
        #pragma unroll
        for (int r = 0; r < 4; ++r) pw[r] = f2b(acc[mi][ni][r] * inv);
        int chp = (mi * 2 + (g >> 1)) ^ (q & 7);
        *(u16x4*)(Lh + q * 64 + chp * 8 + (g & 1) * 4) = pw;
      }
    }

    f32x4 acc2[4][2] = {};
    #pragma unroll
    for (int ks = 0; ks < 2; ++ks) {
      bf16x8 pa[4];
      #pragma unroll
      for (int qi = 0; qi < 4; ++qi) {
        int q = qi * 16 + c;
        int chk = (ks * 4 + g) ^ (q & 7);
        pa[qi] = *(const bf16x8*)(Lh + q * 64 + chk * 8);
      }
      bf16x8 vb[2];
      #pragma unroll
      for (int di = 0; di < 2; ++di) {
        #pragma unroll
        for (int j = 0; j < 8; ++j) {
          int k = ks * 32 + g * 8 + j;
          int chv = ((di * 2 + (c >> 3)) ^ g);
          vb[di][j] = Lh[4096 + k * 32 + chv * 8 + (c & 7)];
        }
      }
      #pragma unroll
      for (int qi = 0; qi < 4; ++qi)
        #pragma unroll
        for (int di = 0; di < 2; ++di)
          acc2[qi][di] = __builtin_amdgcn_mfma_f32_16x16x32_bf16(pa[qi], vb[di], acc2[qi][di], 0, 0, 0);
    }

    // write attn-out into ao (= xn region, dead after QKV)
    #pragma unroll
    for (int qi = 0; qi < 4; ++qi) {
      #pragma unroll
      for (int r = 0; r < 4; ++r) {
        int tok = qi * 16 + g * 4 + r;
        int f = (tok & 15) >> 1;
        #pragma unroll
        for (int di = 0; di < 2; ++di) {
          int ch = h * 32 + di * 16 + c;
          xn[tok * 128 + (((ch >> 3) ^ f) << 3) + (ch & 7)] =
              (short)f2b(acc2[qi][di][r]);
        }
      }
    }
  }
  __syncthreads();

  // ================= proj GEMM + scatter epilogue =================
  {
    f32x4 accp[4][2] = {};
    #pragma unroll
    for (int ks = 0; ks < 4; ++ks) {
      bf16x8 afp[4];
      #pragma unroll
      for (int mi = 0; mi < 4; ++mi) {
        int row = mi * 16 + c;
        afp[mi] = *(const bf16x8*)(xn + row * 128 +
                   (((ks * 4 + g) ^ ((row & 15) >> 1)) << 3));
      }
      bf16x8 wfp[2];
      #pragma unroll
      for (int ni = 0; ni < 2; ++ni)
        wfp[ni] = *(const bf16x8*)(w_prj +
            (size_t)(wv * 32 + ni * 16 + c) * 128 + ks * 32 + g * 8);
      #pragma unroll
      for (int mi = 0; mi < 4; ++mi)
        #pragma unroll
        for (int ni = 0; ni < 2; ++ni)
          accp[mi][ni] = __builtin_amdgcn_mfma_f32_16x16x32_bf16(
              afp[mi], wfp[ni], accp[mi][ni], 0, 0, 0);
    }
    float pb[2];
    pb[0] = proj_b[wv * 32 + c];
    pb[1] = proj_b[wv * 32 + 16 + c];
    #pragma unroll
    for (int mi = 0; mi < 4; ++mi) {
      #pragma unroll
      for (int r = 0; r < 4; ++r) {
        int tok = mi * 16 + g * 4 + r;
        if (tok < 54) {
          if (tok < 5) {
            #pragma unroll
            for (int ni = 0; ni < 2; ++ni) {
              int gcol = wv * 32 + ni * 16 + c;
              pbuf[((size_t)gi * 5 + tok) * 128 + gcol] = accp[mi][ni][r] + pb[ni];
            }
          } else {
            int b = gi >> 6, tt = tok - 5;
            int rr2 = (w >> 3) * 7 + tt / 7 + 3; if (rr2 >= 56) rr2 -= 56;
            int cc = (w & 7) * 7 + tt % 7 + 3;   if (cc >= 56) cc -= 56;
            size_t ob = ((size_t)b * 3141 + 5 + rr2 * 56 + cc) * 128;
            #pragma unroll
            for (int ni = 0; ni < 2; ++ni) {
              int gcol = wv * 32 + ni * 16 + c;
              out[ob + gcol] = x[ob + gcol] + accp[mi][ni][r] + pb[ni];
            }
          }
        }
      }
    }
  }
}

// ---------------------------------------------------------------------------
// Prompt mean over windows + residual
// ---------------------------------------------------------------------------
__global__ __launch_bounds__(128) void prompt_reduce(const float* __restrict__ x,
    const float* __restrict__ pbuf, float* __restrict__ out)
{
  int bp = blockIdx.x;
  int b = bp / 5, p = bp % 5;
  int c = threadIdx.x;
  float s = 0.f;
  for (int w = 0; w < 64; ++w)
    s += pbuf[((size_t)(w * 64 + b) * 5 + p) * 128 + c];
  size_t oidx = ((size_t)b * 3141 + p) * 128 + c;
  out[oidx] = x[oidx] + s * (1.f / 64.f);
}

// ---------------------------------------------------------------------------
// MLP helpers (unchanged from round 8)
// ---------------------------------------------------------------------------
__device__ __forceinline__ void mlp_fc1(const short* __restrict__ xn,
    short* __restrict__ dst, const __hip_bfloat16* __restrict__ w1t,
    const float* __restrict__ b1, int s, int wv, int c, int g)
{
  bf16x8 wf[4][2];
  #pragma unroll
  for (int ks = 0; ks < 4; ++ks)
    #pragma unroll
    for (int ni = 0; ni < 2; ++ni)
      wf[ks][ni] = *(const bf16x8*)(w1t +
          (size_t)(s * 128 + wv * 32 + ni * 16 + c) * 128 + ks * 32 + g * 8);
  f32x4 acc1[4][2] = {};
  #pragma unroll
  for (int ks = 0; ks < 4; ++ks) {
    bf16x8 af[4];
    #pragma unroll
    for (int mi = 0; mi < 4; ++mi) {
      int row = mi * 16 + c;
      af[mi] = *(const bf16x8*)(xn + row * 128 +
                                (((ks * 4 + g) ^ ((row & 15) >> 1)) << 3));
    }
    #pragma unroll
    for (int mi = 0; mi < 4; ++mi)
      #pragma unroll
      for (int ni = 0; ni < 2; ++ni)
        acc1[mi][ni] = __builtin_amdgcn_mfma_f32_16x16x32_bf16(
            af[mi], wf[ks][ni], acc1[mi][ni], 0, 0, 0);
  }
  #pragma unroll
  for (int ni = 0; ni < 2; ++ni) {
    int col = wv * 32 + ni * 16 + c;
    float bv = b1[s * 128 + col];
    #pragma unroll
    for (int mi = 0; mi < 4; ++mi) {
      #pragma unroll
      for (int r = 0; r < 4; ++r) {
        int row = mi * 16 + g * 4 + r;
        float t = acc1[mi][ni][r] + bv;
        float u = t * (0.7978845608028654f + 0.0356774081f * t * t);
        float e = exp2f(-2.8853900817779268f * u);
        t = t * __builtin_amdgcn_rcpf(1.0f + e);
        dst[row * 128 + (((col >> 3) ^ ((row & 15) >> 1)) << 3) + (col & 7)] =
            (short)f2b(t);
      }
    }
  }
}

__device__ __forceinline__ void mlp_fc2(const short* __restrict__ hsrc,
    const __hip_bfloat16* __restrict__ w2t, f32x4 (&acc2)[4][2],
    int s, int wv, int c, int g)
{
  bf16x8 wf[4][2];
  #pragma unroll
  for (int ks = 0; ks < 4; ++ks)
    #pragma unroll
    for (int ni = 0; ni < 2; ++ni)
      wf[ks][ni] = *(const bf16x8*)(w2t +
          (size_t)(wv * 32 + ni * 16 + c) * 512 + s * 128 + ks * 32 + g * 8);
  #pragma unroll
  for (int ks = 0; ks < 4; ++ks) {
    bf16x8 af[4];
    #pragma unroll
    for (int mi = 0; mi < 4; ++mi) {
      int row = mi * 16 + c;
      af[mi] = *(const bf16x8*)(hsrc + row * 128 +
                                (((ks * 4 + g) ^ ((row & 15) >> 1)) << 3));
    }
    #pragma unroll
    for (int mi = 0; mi < 4; ++mi)
      #pragma unroll
      for (int ni = 0; ni < 2; ++ni)
        acc2[mi][ni] = __builtin_amdgcn_mfma_f32_16x16x32_bf16(
            af[mi], wf[ks][ni], acc2[mi][ni], 0, 0, 0);
  }
}

// ---------------------------------------------------------------------------
// Fused MLP (unchanged from round 8): pipelined strips, dbuf h, 48KB LDS.
// ---------------------------------------------------------------------------
__global__ __launch_bounds__(256, 3) void mlp_fused(
    const float* __restrict__ xin,
    const float* __restrict__ gamma, const float* __restrict__ beta,
    const __hip_bfloat16* __restrict__ w1t, const float* __restrict__ b1,
    const __hip_bfloat16* __restrict__ w2t, const float* __restrict__ b2,
    float* __restrict__ outp)
{
  __shared__ short xn[8192];
  __shared__ short hb[2][8192];
  const int tid = threadIdx.x;
  const int wv = tid >> 6, lane = tid & 63;
  const int c = lane & 15, g = lane >> 4;
  const int r0 = blockIdx.x * 64;

  for (int rr = 0; rr < 16; ++rr) {
    int row = wv * 16 + rr;
    const float* xr = xin + (size_t)(r0 + row) * 128;
    float v0 = xr[lane], v1 = xr[lane + 64];
    float s = v0 + v1, s2 = v0 * v0 + v1 * v1;
    #pragma unroll
    for (int off = 32; off > 0; off >>= 1) {
      s  += __shfl_xor(s,  off);
      s2 += __shfl_xor(s2, off);
    }
    float mu = s * (1.f / 128.f);
    float var = s2 * (1.f / 128.f) - mu * mu;
    float rs = rsqrtf(var + 1e-5f);
    float y0 = (v0 - mu) * rs * gamma[lane]      + beta[lane];
    float y1 = (v1 - mu) * rs * gamma[lane + 64] + beta[lane + 64];
    int f = (row & 15) >> 1;
    int ca = lane, cb = lane + 64;
    xn[row * 128 + (((ca >> 3) ^ f) << 3) + (ca & 7)] = (short)f2b(y0);
    xn[row * 128 + (((cb >> 3) ^ f) << 3) + (cb & 7)] = (short)f2b(y1);
  }
  __syncthreads();

  mlp_fc1(xn, hb[0], w1t, b1, 0, wv, c, g);
  __syncthreads();

  f32x4 acc2[4][2] = {};
  #pragma unroll
  for (int s = 0; s < 4; ++s) {
    if (s < 3) mlp_fc1(xn, hb[(s + 1) & 1], w1t, b1, s + 1, wv, c, g);
    mlp_fc2(hb[s & 1], w2t, acc2, s, wv, c, g);
    if (s < 3) __syncthreads();
  }

  #pragma unroll
  for (int mi = 0; mi < 4; ++mi) {
    #pragma unroll
    for (int r = 0; r < 4; ++r) {
      int row = r0 + mi * 16 + g * 4 + r;
      #pragma unroll
      for (int ni = 0; ni < 2; ++ni) {
        int col = wv * 32 + ni * 16 + c;
        size_t o = (size_t)row * 128 + col;
        outp[o] = acc2[mi][ni][r] + b2[col] + xin[o];
      }
    }
  }
}

// ---------------------------------------------------------------------------
// Launch
// ---------------------------------------------------------------------------
extern "C" void kernel_launch(void* const* d_in, const int* in_sizes, int n_in,
                              void* d_out, int out_size, void* d_ws, size_t ws_size,
                              hipStream_t stream) {
  const float* x      = (const float*)d_in[0];
  const float* n1g    = (const float*)d_in[1];
  const float* n1b    = (const float*)d_in[2];
  const float* qkv_w  = (const float*)d_in[3];
  const float* qkv_b  = (const float*)d_in[4];
  const float* proj_w = (const float*)d_in[5];
  const float* proj_b = (const float*)d_in[6];
  const float* rpb    = (const float*)d_in[7];
  const float* n2g    = (const float*)d_in[8];
  const float* n2b    = (const float*)d_in[9];
  const float* fc1w   = (const float*)d_in[10];
  const float* fc1b   = (const float*)d_in[11];
  const float* fc2w   = (const float*)d_in[12];
  const float* fc2b   = (const float*)d_in[13];
  float* out = (float*)d_out;
  char* ws = (char*)d_ws;

  __hip_bfloat16* wbuf = (__hip_bfloat16*)ws;
  __hip_bfloat16* w_qkv = wbuf;                 // [384][128]
  __hip_bfloat16* w_prj = wbuf + 49152;         // [128][128]
  __hip_bfloat16* w_fc1 = wbuf + 65536;         // [512][128]
  __hip_bfloat16* w_fc2 = wbuf + 131072;        // [128][512]
  __hip_bfloat16* bias_tab = (__hip_bfloat16*)(ws + 393216);
  float* pbuf = (float*)(ws + 2490368);         // 4096*5*128 f32 = 10.5 MB

  hipLaunchKernelGGL(convert_wt, dim3(192), dim3(256), 0, stream, qkv_w, w_qkv, 128, 384);
  hipLaunchKernelGGL(convert_wt, dim3(64),  dim3(256), 0, stream, proj_w, w_prj, 128, 128);
  hipLaunchKernelGGL(convert_wt, dim3(256), dim3(256), 0, stream, fc1w,  w_fc1, 128, 512);
  hipLaunchKernelGGL(convert_wt, dim3(256), dim3(256), 0, stream, fc2w,  w_fc2, 512, 128);
  hipLaunchKernelGGL(bias_gen, dim3(256), dim3(256), 0, stream, rpb, bias_tab);

  // Phase 1: fully fused (no intermediate HBM traffic)
  hipLaunchKernelGGL(phase1_fused, dim3(4096), dim3(256), 0, stream,
                     x, n1g, n1b, w_qkv, qkv_b, w_prj, proj_b, bias_tab, out, pbuf);
  hipLaunchKernelGGL(prompt_reduce, dim3(320), dim3(128), 0, stream, x, pbuf, out);

  // Phase 2: fused MLP (in-place on out), 201024 = 3141*64 rows
  hipLaunchKernelGGL(mlp_fused, dim3(3141), dim3(256), 0, stream,
                     out, n2g, n2b, w_fc1, fc1b, w_fc2, fc2b, out);
  (void)in_sizes; (void)n_in; (void)out_size; (void)ws_size;
}

// Round 10
// 356.763 us; speedup vs baseline: 1.3512x; 1.0740x over previous
//
#include <hip/hip_runtime.h>
#include <hip/hip_bf16.h>
#include <math.h>

// H=W=56, C=128, WS=7, SS=3, NH=4, P=5, HD=32, NW=64, NTOK=49, N=54, B=64
// x rows: 3141 = 5 + 56*56; window-rows: 4096 = B*NW; tokens/window: 54

typedef __attribute__((ext_vector_type(8))) short bf16x8;
typedef __attribute__((ext_vector_type(4))) float f32x4;
typedef __attribute__((ext_vector_type(4))) unsigned short u16x4;

__device__ __forceinline__ float bf2f(unsigned short u) {
  union { unsigned int i; float f; } v; v.i = ((unsigned)u) << 16; return v.f;
}
__device__ __forceinline__ unsigned short f2b(float f) {
  __hip_bfloat16 b = __float2bfloat16(f);
  return *reinterpret_cast<unsigned short*>(&b);
}

// ---------------------------------------------------------------------------
// Weight convert: wt[n][k] = bf16(w[k][n])
// ---------------------------------------------------------------------------
__global__ __launch_bounds__(256) void convert_wt(const float* __restrict__ w,
    __hip_bfloat16* __restrict__ wt, int K, int N)
{
  int idx = blockIdx.x * 256 + threadIdx.x;
  if (idx >= N * K) return;
  int n = idx / K, k = idx % K;
  wt[idx] = __float2bfloat16(w[(size_t)k * N + n]);
}

// ---------------------------------------------------------------------------
// Bias table gen (once): bias2[w][h][q][k] bf16, exp2-domain; k>=54 -> -inf
// ---------------------------------------------------------------------------
__global__ __launch_bounds__(256) void bias_gen(const float* __restrict__ rpb,
    __hip_bfloat16* __restrict__ tab)
{
  int w = blockIdx.x >> 2, h = blockIdx.x & 3;
  int wh = w >> 3, ww = w & 7;
  #pragma unroll
  for (int e = 0; e < 16; ++e) {
    int fi = e * 256 + threadIdx.x;
    int q = fi >> 6, k = fi & 63;
    float v;
    if (k >= 54) {
      v = -INFINITY;
    } else {
      v = 0.f;
      if (q >= 5 && q < 54 && k >= 5) {
        int tq = q - 5, tk = k - 5;
        int aq = tq / 7, bq_ = tq % 7, ak = tk / 7, bk = tk % 7;
        int dh = aq - ak + 6, dw = bq_ - bk + 6;
        v = rpb[(dh * 13 + dw) * 4 + h];
        int rq = wh * 7 + aq, cq = ww * 7 + bq_;
        int rk = wh * 7 + ak, ck = ww * 7 + bk;
        int zq = (rq < 49 ? 0 : (rq < 53 ? 1 : 2)) * 3 + (cq < 49 ? 0 : (cq < 53 ? 1 : 2));
        int zk = (rk < 49 ? 0 : (rk < 53 ? 1 : 2)) * 3 + (ck < 49 ? 0 : (ck < 53 ? 1 : 2));
        if (zq != zk) v += -100.f;
      }
      v *= 1.44269504088896f;
    }
    tab[((size_t)blockIdx.x << 12) + fi] = __float2bfloat16(v);
  }
}

// ---------------------------------------------------------------------------
// Phase-1 mega-kernel v2: one block per window-row gi. 4 waves, 48 KB LDS
// (3 blocks/CU). Wave wv owns head wv end-to-end:
//   LN1+gather -> xn(LDS [0,8192) shorts) -> af regs -> barrier ->
//   QKV per-head (writes own 12KB region, overlays xn) -> attention
//   (barrier-free, wave-local) -> barrier -> ao overlay [0,8192) ->
//   barrier -> proj + scatter epilogue.
// ---------------------------------------------------------------------------
__global__ __launch_bounds__(256, 3) void phase1_fused(
    const float* __restrict__ x,
    const float* __restrict__ n1g, const float* __restrict__ n1b,
    const __hip_bfloat16* __restrict__ w_qkv, const float* __restrict__ qkv_b,
    const __hip_bfloat16* __restrict__ w_prj, const float* __restrict__ proj_b,
    const __hip_bfloat16* __restrict__ bias_tab,
    float* __restrict__ out, float* __restrict__ pbuf)
{
  __shared__ short lds[24576];   // 48 KB
  short* xn = lds;               // [64][128] until af loaded; later ao
  const int tid = threadIdx.x;
  const int wv = tid >> 6, lane = tid & 63;
  const int c = lane & 15, g = lane >> 4;
  const int gi = blockIdx.x;
  const int w = gi & 63;
  short* Lh = lds + wv * 6144;   // head wv: Q@0, K@2048, V@4096 (shorts)

  // ================= LN1 + window gather (rows wv, wv+4, ...) =========
  for (int rr = 0; rr < 14; ++rr) {
    int row = wv + rr * 4;
    if (row >= 54) break;
    int src;
    if (row < 5) {
      src = (gi & 63) * 3141 + row;
    } else {
      int b = gi >> 6, t = row - 5;
      int hp = (w >> 3) * 7 + t / 7 + 3; if (hp >= 56) hp -= 56;
      int wp = (w & 7) * 7 + t % 7 + 3;  if (wp >= 56) wp -= 56;
      src = b * 3141 + 5 + hp * 56 + wp;
    }
    const float* xr = x + (size_t)src * 128;
    float v0 = xr[lane], v1 = xr[lane + 64];
    float s = v0 + v1, s2 = v0 * v0 + v1 * v1;
    #pragma unroll
    for (int off = 32; off > 0; off >>= 1) {
      s  += __shfl_xor(s,  off);
      s2 += __shfl_xor(s2, off);
    }
    float mu = s * (1.f / 128.f);
    float var = s2 * (1.f / 128.f) - mu * mu;
    float rs = rsqrtf(var + 1e-5f);
    float y0 = (v0 - mu) * rs * n1g[lane]      + n1b[lane];
    float y1 = (v1 - mu) * rs * n1g[lane + 64] + n1b[lane + 64];
    int f = (row & 15) >> 1;
    int ca = lane, cb = lane + 64;
    xn[row * 128 + (((ca >> 3) ^ f) << 3) + (ca & 7)] = (short)f2b(y0);
    xn[row * 128 + (((cb >> 3) ^ f) << 3) + (cb & 7)] = (short)f2b(y1);
  }
  // zero pad rows 54..63 (QKV A-frags read them; K/V pads masked by bias)
  for (int idx = tid; idx < 1280; idx += 256) xn[54 * 128 + idx] = 0;
  __syncthreads();

  // ================= A-fragments to registers (xn dies after) =========
  bf16x8 af[4][4];
  #pragma unroll
  for (int ks = 0; ks < 4; ++ks)
    #pragma unroll
    for (int mi = 0; mi < 4; ++mi) {
      int row = mi * 16 + c;
      af[ks][mi] = *(const bf16x8*)(xn + row * 128 +
                    (((ks * 4 + g) ^ ((row & 15) >> 1)) << 3));
    }
  __syncthreads();   // xn dead; QL (full 48KB) may now be written

  // ================= QKV GEMM, per-head (wave-local, no barrier) ======
  {
    #pragma unroll
    for (int t = 0; t < 6; ++t) {
      int m = t >> 1;                 // 0=Q, 1=K, 2=V
      int chb = (t & 1) * 16;         // channel base within head
      int n0 = m * 128 + wv * 32 + chb;
      bf16x8 bfr[4];
      #pragma unroll
      for (int ks = 0; ks < 4; ++ks)
        bfr[ks] = *(const bf16x8*)(w_qkv + (size_t)(n0 + c) * 128 + ks * 32 + g * 8);
      f32x4 acct[4] = {};
      #pragma unroll
      for (int ks = 0; ks < 4; ++ks)
        #pragma unroll
        for (int mi = 0; mi < 4; ++mi)
          acct[mi] = __builtin_amdgcn_mfma_f32_16x16x32_bf16(
              af[ks][mi], bfr[ks], acct[mi], 0, 0, 0);
      float bq = qkv_b[n0 + c];
      int cpart = (chb >> 3) + (c >> 3);
      int e = c & 7;
      int base = m * 2048;
      #pragma unroll
      for (int mi = 0; mi < 4; ++mi) {
        #pragma unroll
        for (int r = 0; r < 4; ++r) {
          int tok = mi * 16 + g * 4 + r;
          int swz = (m == 2) ? ((tok >> 3) & 3) : ((tok >> 1) & 3);
          Lh[base + tok * 32 + ((cpart ^ swz) << 3) + e] =
              (short)f2b(acct[mi][r] + bq);
        }
      }
    }
  }

  // ================= attention (wave wv = head wv, barrier-free) ======
  {
    const int h = wv;
    const unsigned short* bt = (const unsigned short*)bias_tab + ((size_t)(w * 4 + h) << 12);
    u16x4 bb[4][4];
    #pragma unroll
    for (int ni = 0; ni < 4; ++ni)
      #pragma unroll
      for (int mi = 0; mi < 4; ++mi)
        bb[ni][mi] = *(const u16x4*)(bt + (ni * 16 + c) * 64 + mi * 16 + g * 4);

    bf16x8 kf[4], bq[4];
    #pragma unroll
    for (int mi = 0; mi < 4; ++mi) {
      int tok = mi * 16 + c;
      kf[mi] = *(const bf16x8*)(Lh + 2048 + tok * 32 + ((g ^ ((tok >> 1) & 3)) << 3));
    }
    #pragma unroll
    for (int ni = 0; ni < 4; ++ni) {
      int q = ni * 16 + c;
      bq[ni] = *(const bf16x8*)(Lh + q * 32 + ((g ^ ((q >> 1) & 3)) << 3));
    }
    f32x4 acc[4][4] = {};
    __builtin_amdgcn_s_setprio(1);
    #pragma unroll
    for (int mi = 0; mi < 4; ++mi)
      #pragma unroll
      for (int ni = 0; ni < 4; ++ni)
        acc[mi][ni] = __builtin_amdgcn_mfma_f32_16x16x32_bf16(kf[mi], bq[ni], acc[mi][ni], 0, 0, 0);
    __builtin_amdgcn_s_setprio(0);

    const float SC = 0.17677669529663689f * 1.44269504088896f;
    #pragma unroll
    for (int ni = 0; ni < 4; ++ni)
      #pragma unroll
      for (int mi = 0; mi < 4; ++mi)
        #pragma unroll
        for (int r = 0; r < 4; ++r)
          acc[mi][ni][r] = acc[mi][ni][r] * SC + bf2f(bb[ni][mi][r]);

    #pragma unroll
    for (int ni = 0; ni < 4; ++ni) {
      float m2 = -3.0e38f;
      #pragma unroll
      for (int mi = 0; mi < 4; ++mi)
        #pragma unroll
        for (int r = 0; r < 4; ++r)
          m2 = fmaxf(m2, acc[mi][ni][r]);
      m2 = fmaxf(m2, __shfl_xor(m2, 16, 64));
      m2 = fmaxf(m2, __shfl_xor(m2, 32, 64));
      float sm = 0.f;
      #pragma unroll
      for (int mi = 0; mi < 4; ++mi)
        #pragma unroll
        for (int r = 0; r < 4; ++r) {
          float p = exp2f(acc[mi][ni][r] - m2);
          acc[mi][ni][r] = p;
          sm += p;
        }
      sm += __shfl_xor(sm, 16, 64);
      sm += __shfl_xor(sm, 32, 64);
      float inv = 1.0f / sm;
      int q = ni * 16 + c;
      #pragma unroll
      for (int mi = 0; mi < 4; ++mi) {
        u16x4 pw;
        #pragma unroll
        for (int r = 0; r < 4; ++r) pw[r] = f2b(acc[mi][ni][r] * inv);
        int chp = (mi * 2 + (g >> 1)) ^ (q & 7);
        *(u16x4*)(Lh + q * 64 + chp * 8 + (g & 1) * 4) = pw;
      }
    }

    f32x4 acc2[4][2] = {};
    #pragma unroll
    for (int ks = 0; ks < 2; ++ks) {
      bf16x8 pa[4];
      #pragma unroll
      for (int qi = 0; qi < 4; ++qi) {
        int q = qi * 16 + c;
        int chk = (ks * 4 + g) ^ (q & 7);
        pa[qi] = *(const bf16x8*)(Lh + q * 64 + chk * 8);
      }
      bf16x8 vb[2];
      #pragma unroll
      for (int di = 0; di < 2; ++di) {
        #pragma unroll
        for (int j = 0; j < 8; ++j) {
          int k = ks * 32 + g * 8 + j;
          int chv = ((di * 2 + (c >> 3)) ^ g);
          vb[di][j] = Lh[4096 + k * 32 + chv * 8 + (c & 7)];
        }
      }
      __builtin_amdgcn_s_setprio(1);
      #pragma unroll
      for (int qi = 0; qi < 4; ++qi)
        #pragma unroll
        for (int di = 0; di < 2; ++di)
          acc2[qi][di] = __builtin_amdgcn_mfma_f32_16x16x32_bf16(pa[qi], vb[di], acc2[qi][di], 0, 0, 0);
      __builtin_amdgcn_s_setprio(0);
    }

    __syncthreads();   // all waves done with Q/K/Ps regions -> ao overlay safe
    // write attn-out into ao (= lds[0,8192), dead Q/K/Ps of heads 0/1)
    #pragma unroll
    for (int qi = 0; qi < 4; ++qi) {
      #pragma unroll
      for (int r = 0; r < 4; ++r) {
        int tok = qi * 16 + g * 4 + r;
        int f = (tok & 15) >> 1;
        #pragma unroll
        for (int di = 0; di < 2; ++di) {
          int ch = h * 32 + di * 16 + c;
          xn[tok * 128 + (((ch >> 3) ^ f) << 3) + (ch & 7)] =
              (short)f2b(acc2[qi][di][r]);
        }
      }
    }
  }
  __syncthreads();

  // ================= proj GEMM + scatter epilogue =====================
  {
    f32x4 accp[4][2] = {};
    #pragma unroll
    for (int ks = 0; ks < 4; ++ks) {
      bf16x8 afp[4];
      #pragma unroll
      for (int mi = 0; mi < 4; ++mi) {
        int row = mi * 16 + c;
        afp[mi] = *(const bf16x8*)(xn + row * 128 +
                   (((ks * 4 + g) ^ ((row & 15) >> 1)) << 3));
      }
      bf16x8 wfp[2];
      #pragma unroll
      for (int ni = 0; ni < 2; ++ni)
        wfp[ni] = *(const bf16x8*)(w_prj +
            (size_t)(wv * 32 + ni * 16 + c) * 128 + ks * 32 + g * 8);
      #pragma unroll
      for (int mi = 0; mi < 4; ++mi)
        #pragma unroll
        for (int ni = 0; ni < 2; ++ni)
          accp[mi][ni] = __builtin_amdgcn_mfma_f32_16x16x32_bf16(
              afp[mi], wfp[ni], accp[mi][ni], 0, 0, 0);
    }
    float pb[2];
    pb[0] = proj_b[wv * 32 + c];
    pb[1] = proj_b[wv * 32 + 16 + c];
    #pragma unroll
    for (int mi = 0; mi < 4; ++mi) {
      #pragma unroll
      for (int r = 0; r < 4; ++r) {
        int tok = mi * 16 + g * 4 + r;
        if (tok < 54) {
          if (tok < 5) {
            #pragma unroll
            for (int ni = 0; ni < 2; ++ni) {
              int gcol = wv * 32 + ni * 16 + c;
              pbuf[((size_t)gi * 5 + tok) * 128 + gcol] = accp[mi][ni][r] + pb[ni];
            }
          } else {
            int b = gi >> 6, tt = tok - 5;
            int rr2 = (w >> 3) * 7 + tt / 7 + 3; if (rr2 >= 56) rr2 -= 56;
            int cc = (w & 7) * 7 + tt % 7 + 3;   if (cc >= 56) cc -= 56;
            size_t ob = ((size_t)b * 3141 + 5 + rr2 * 56 + cc) * 128;
            #pragma unroll
            for (int ni = 0; ni < 2; ++ni) {
              int gcol = wv * 32 + ni * 16 + c;
              out[ob + gcol] = x[ob + gcol] + accp[mi][ni][r] + pb[ni];
            }
          }
        }
      }
    }
  }
}

// ---------------------------------------------------------------------------
// Prompt mean over windows + residual
// ---------------------------------------------------------------------------
__global__ __launch_bounds__(128) void prompt_reduce(const float* __restrict__ x,
    const float* __restrict__ pbuf, float* __restrict__ out)
{
  int bp = blockIdx.x;
  int b = bp / 5, p = bp % 5;
  int c = threadIdx.x;
  float s = 0.f;
  for (int w = 0; w < 64; ++w)
    s += pbuf[((size_t)(w * 64 + b) * 5 + p) * 128 + c];
  size_t oidx = ((size_t)b * 3141 + p) * 128 + c;
  out[oidx] = x[oidx] + s * (1.f / 64.f);
}

// ---------------------------------------------------------------------------
// MLP helpers (unchanged)
// ---------------------------------------------------------------------------
__device__ __forceinline__ void mlp_fc1(const short* __restrict__ xn,
    short* __restrict__ dst, const __hip_bfloat16* __restrict__ w1t,
    const float* __restrict__ b1, int s, int wv, int c, int g)
{
  bf16x8 wf[4][2];
  #pragma unroll
  for (int ks = 0; ks < 4; ++ks)
    #pragma unroll
    for (int ni = 0; ni < 2; ++ni)
      wf[ks][ni] = *(const bf16x8*)(w1t +
          (size_t)(s * 128 + wv * 32 + ni * 16 + c) * 128 + ks * 32 + g * 8);
  f32x4 acc1[4][2] = {};
  #pragma unroll
  for (int ks = 0; ks < 4; ++ks) {
    bf16x8 af[4];
    #pragma unroll
    for (int mi = 0; mi < 4; ++mi) {
      int row = mi * 16 + c;
      af[mi] = *(const bf16x8*)(xn + row * 128 +
                                (((ks * 4 + g) ^ ((row & 15) >> 1)) << 3));
    }
    #pragma unroll
    for (int mi = 0; mi < 4; ++mi)
      #pragma unroll
      for (int ni = 0; ni < 2; ++ni)
        acc1[mi][ni] = __builtin_amdgcn_mfma_f32_16x16x32_bf16(
            af[mi], wf[ks][ni], acc1[mi][ni], 0, 0, 0);
  }
  #pragma unroll
  for (int ni = 0; ni < 2; ++ni) {
    int col = wv * 32 + ni * 16 + c;
    float bv = b1[s * 128 + col];
    #pragma unroll
    for (int mi = 0; mi < 4; ++mi) {
      #pragma unroll
      for (int r = 0; r < 4; ++r) {
        int row = mi * 16 + g * 4 + r;
        float t = acc1[mi][ni][r] + bv;
        float u = t * (0.7978845608028654f + 0.0356774081f * t * t);
        float e = exp2f(-2.8853900817779268f * u);
        t = t * __builtin_amdgcn_rcpf(1.0f + e);
        dst[row * 128 + (((col >> 3) ^ ((row & 15) >> 1)) << 3) + (col & 7)] =
            (short)f2b(t);
      }
    }
  }
}

__device__ __forceinline__ void mlp_fc2(const short* __restrict__ hsrc,
    const __hip_bfloat16* __restrict__ w2t, f32x4 (&acc2)[4][2],
    int s, int wv, int c, int g)
{
  bf16x8 wf[4][2];
  #pragma unroll
  for (int ks = 0; ks < 4; ++ks)
    #pragma unroll
    for (int ni = 0; ni < 2; ++ni)
      wf[ks][ni] = *(const bf16x8*)(w2t +
          (size_t)(wv * 32 + ni * 16 + c) * 512 + s * 128 + ks * 32 + g * 8);
  #pragma unroll
  for (int ks = 0; ks < 4; ++ks) {
    bf16x8 af[4];
    #pragma unroll
    for (int mi = 0; mi < 4; ++mi) {
      int row = mi * 16 + c;
      af[mi] = *(const bf16x8*)(hsrc + row * 128 +
                                (((ks * 4 + g) ^ ((row & 15) >> 1)) << 3));
    }
    #pragma unroll
    for (int mi = 0; mi < 4; ++mi)
      #pragma unroll
      for (int ni = 0; ni < 2; ++ni)
        acc2[mi][ni] = __builtin_amdgcn_mfma_f32_16x16x32_bf16(
            af[mi], wf[ks][ni], acc2[mi][ni], 0, 0, 0);
  }
}

// ---------------------------------------------------------------------------
// Fused MLP (unchanged): pipelined strips, dbuf h, 48KB LDS.
// ---------------------------------------------------------------------------
__global__ __launch_bounds__(256, 3) void mlp_fused(
    const float* __restrict__ xin,
    const float* __restrict__ gamma, const float* __restrict__ beta,
    const __hip_bfloat16* __restrict__ w1t, const float* __restrict__ b1,
    const __hip_bfloat16* __restrict__ w2t, const float* __restrict__ b2,
    float* __restrict__ outp)
{
  __shared__ short xn[8192];
  __shared__ short hb[2][8192];
  const int tid = threadIdx.x;
  const int wv = tid >> 6, lane = tid & 63;
  const int c = lane & 15, g = lane >> 4;
  const int r0 = blockIdx.x * 64;

  for (int rr = 0; rr < 16; ++rr) {
    int row = wv * 16 + rr;
    const float* xr = xin + (size_t)(r0 + row) * 128;
    float v0 = xr[lane], v1 = xr[lane + 64];
    float s = v0 + v1, s2 = v0 * v0 + v1 * v1;
    #pragma unroll
    for (int off = 32; off > 0; off >>= 1) {
      s  += __shfl_xor(s,  off);
      s2 += __shfl_xor(s2, off);
    }
    float mu = s * (1.f / 128.f);
    float var = s2 * (1.f / 128.f) - mu * mu;
    float rs = rsqrtf(var + 1e-5f);
    float y0 = (v0 - mu) * rs * gamma[lane]      + beta[lane];
    float y1 = (v1 - mu) * rs * gamma[lane + 64] + beta[lane + 64];
    int f = (row & 15) >> 1;
    int ca = lane, cb = lane + 64;
    xn[row * 128 + (((ca >> 3) ^ f) << 3) + (ca & 7)] = (short)f2b(y0);
    xn[row * 128 + (((cb >> 3) ^ f) << 3) + (cb & 7)] = (short)f2b(y1);
  }
  __syncthreads();

  mlp_fc1(xn, hb[0], w1t, b1, 0, wv, c, g);
  __syncthreads();

  f32x4 acc2[4][2] = {};
  #pragma unroll
  for (int s = 0; s < 4; ++s) {
    if (s < 3) mlp_fc1(xn, hb[(s + 1) & 1], w1t, b1, s + 1, wv, c, g);
    mlp_fc2(hb[s & 1], w2t, acc2, s, wv, c, g);
    if (s < 3) __syncthreads();
  }

  #pragma unroll
  for (int mi = 0; mi < 4; ++mi) {
    #pragma unroll
    for (int r = 0; r < 4; ++r) {
      int row = r0 + mi * 16 + g * 4 + r;
      #pragma unroll
      for (int ni = 0; ni < 2; ++ni) {
        int col = wv * 32 + ni * 16 + c;
        size_t o = (size_t)row * 128 + col;
        outp[o] = acc2[mi][ni][r] + b2[col] + xin[o];
      }
    }
  }
}

// ---------------------------------------------------------------------------
// Launch
// ---------------------------------------------------------------------------
extern "C" void kernel_launch(void* const* d_in, const int* in_sizes, int n_in,
                              void* d_out, int out_size, void* d_ws, size_t ws_size,
                              hipStream_t stream) {
  const float* x      = (const float*)d_in[0];
  const float* n1g    = (const float*)d_in[1];
  const float* n1b    = (const float*)d_in[2];
  const float* qkv_w  = (const float*)d_in[3];
  const float* qkv_b  = (const float*)d_in[4];
  const float* proj_w = (const float*)d_in[5];
  const float* proj_b = (const float*)d_in[6];
  const float* rpb    = (const float*)d_in[7];
  const float* n2g    = (const float*)d_in[8];
  const float* n2b    = (const float*)d_in[9];
  const float* fc1w   = (const float*)d_in[10];
  const float* fc1b   = (const float*)d_in[11];
  const float* fc2w   = (const float*)d_in[12];
  const float* fc2b   = (const float*)d_in[13];
  float* out = (float*)d_out;
  char* ws = (char*)d_ws;

  __hip_bfloat16* wbuf = (__hip_bfloat16*)ws;
  __hip_bfloat16* w_qkv = wbuf;                 // [384][128]
  __hip_bfloat16* w_prj = wbuf + 49152;         // [128][128]
  __hip_bfloat16* w_fc1 = wbuf + 65536;         // [512][128]
  __hip_bfloat16* w_fc2 = wbuf + 131072;        // [128][512]
  __hip_bfloat16* bias_tab = (__hip_bfloat16*)(ws + 393216);
  float* pbuf = (float*)(ws + 2490368);         // 4096*5*128 f32 = 10.5 MB

  hipLaunchKernelGGL(convert_wt, dim3(192), dim3(256), 0, stream, qkv_w, w_qkv, 128, 384);
  hipLaunchKernelGGL(convert_wt, dim3(64),  dim3(256), 0, stream, proj_w, w_prj, 128, 128);
  hipLaunchKernelGGL(convert_wt, dim3(256), dim3(256), 0, stream, fc1w,  w_fc1, 128, 512);
  hipLaunchKernelGGL(convert_wt, dim3(256), dim3(256), 0, stream, fc2w,  w_fc2, 512, 128);
  hipLaunchKernelGGL(bias_gen, dim3(256), dim3(256), 0, stream, rpb, bias_tab);

  // Phase 1: fully fused (no intermediate HBM traffic)
  hipLaunchKernelGGL(phase1_fused, dim3(4096), dim3(256), 0, stream,
                     x, n1g, n1b, w_qkv, qkv_b, w_prj, proj_b, bias_tab, out, pbuf);
  hipLaunchKernelGGL(prompt_reduce, dim3(320), dim3(128), 0, stream, x, pbuf, out);

  // Phase 2: fused MLP (in-place on out), 201024 = 3141*64 rows
  hipLaunchKernelGGL(mlp_fused, dim3(3141), dim3(256), 0, stream,
                     out, n2g, n2b, w_fc1, fc1b, w_fc2, fc2b, out);
  (void)in_sizes; (void)n_in; (void)out_size; (void)ws_size;
}

// Round 11
// 323.806 us; speedup vs baseline: 1.4887x; 1.1018x over previous
//
#include <hip/hip_runtime.h>
#include <hip/hip_bf16.h>
#include <math.h>

// H=W=56, C=128, WS=7, SS=3, NH=4, P=5, HD=32, NW=64, NTOK=49, N=54, B=64
// x rows: 3141 = 5 + 56*56; window-rows: 4096 = B*NW; tokens/window: 54

typedef __attribute__((ext_vector_type(8))) short bf16x8;
typedef __attribute__((ext_vector_type(4))) float f32x4;
typedef __attribute__((ext_vector_type(4))) unsigned short u16x4;

__device__ __forceinline__ float bf2f(unsigned short u) {
  union { unsigned int i; float f; } v; v.i = ((unsigned)u) << 16; return v.f;
}
__device__ __forceinline__ unsigned short f2b(float f) {
  __hip_bfloat16 b = __float2bfloat16(f);
  return *reinterpret_cast<unsigned short*>(&b);
}

// ---------------------------------------------------------------------------
// Weight convert: wt[n][k] = bf16(w[k][n])
// ---------------------------------------------------------------------------
__global__ __launch_bounds__(256) void convert_wt(const float* __restrict__ w,
    __hip_bfloat16* __restrict__ wt, int K, int N)
{
  int idx = blockIdx.x * 256 + threadIdx.x;
  if (idx >= N * K) return;
  int n = idx / K, k = idx % K;
  wt[idx] = __float2bfloat16(w[(size_t)k * N + n]);
}

// ---------------------------------------------------------------------------
// Bias table gen (once): bias2[w][h][q][k] bf16, exp2-domain; k>=54 -> -inf
// ---------------------------------------------------------------------------
__global__ __launch_bounds__(256) void bias_gen(const float* __restrict__ rpb,
    __hip_bfloat16* __restrict__ tab)
{
  int w = blockIdx.x >> 2, h = blockIdx.x & 3;
  int wh = w >> 3, ww = w & 7;
  #pragma unroll
  for (int e = 0; e < 16; ++e) {
    int fi = e * 256 + threadIdx.x;
    int q = fi >> 6, k = fi & 63;
    float v;
    if (k >= 54) {
      v = -INFINITY;
    } else {
      v = 0.f;
      if (q >= 5 && q < 54 && k >= 5) {
        int tq = q - 5, tk = k - 5;
        int aq = tq / 7, bq_ = tq % 7, ak = tk / 7, bk = tk % 7;
        int dh = aq - ak + 6, dw = bq_ - bk + 6;
        v = rpb[(dh * 13 + dw) * 4 + h];
        int rq = wh * 7 + aq, cq = ww * 7 + bq_;
        int rk = wh * 7 + ak, ck = ww * 7 + bk;
        int zq = (rq < 49 ? 0 : (rq < 53 ? 1 : 2)) * 3 + (cq < 49 ? 0 : (cq < 53 ? 1 : 2));
        int zk = (rk < 49 ? 0 : (rk < 53 ? 1 : 2)) * 3 + (ck < 49 ? 0 : (ck < 53 ? 1 : 2));
        if (zq != zk) v += -100.f;
      }
      v *= 1.44269504088896f;
    }
    tab[((size_t)blockIdx.x << 12) + fi] = __float2bfloat16(v);
  }
}

// ---------------------------------------------------------------------------
// Phase-1 mega-kernel v3: one block per window-row gi. 4 waves, 48 KB LDS.
// Wave wv owns head wv end-to-end. Transposed (swapped-operand) MFMA stores:
// QKV/ao writes are u16x4 packs (4 consecutive channels per token).
// ---------------------------------------------------------------------------
__global__ __launch_bounds__(256, 3) void phase1_fused(
    const float* __restrict__ x,
    const float* __restrict__ n1g, const float* __restrict__ n1b,
    const __hip_bfloat16* __restrict__ w_qkv, const float* __restrict__ qkv_b,
    const __hip_bfloat16* __restrict__ w_prj, const float* __restrict__ proj_b,
    const __hip_bfloat16* __restrict__ bias_tab,
    float* __restrict__ out, float* __restrict__ pbuf)
{
  __shared__ short lds[24576];   // 48 KB
  short* xn = lds;               // [64][128] until af loaded; later ao
  const int tid = threadIdx.x;
  const int wv = tid >> 6, lane = tid & 63;
  const int c = lane & 15, g = lane >> 4;
  const int gi = blockIdx.x;
  const int w = gi & 63;
  short* Lh = lds + wv * 6144;   // head wv: Q@0, K@2048, V@4096 (shorts)

  // ================= LN1 + window gather (rows wv, wv+4, ...) =========
  // Phase A: issue all loads (unrolled, predicated -> all in flight)
  float v0a[14], v1a[14];
  #pragma unroll
  for (int rr = 0; rr < 14; ++rr) {
    int row = wv + rr * 4;
    int rowc = (row < 54) ? row : 0;
    int src;
    if (rowc < 5) {
      src = (gi & 63) * 3141 + rowc;
    } else {
      int b = gi >> 6, t = rowc - 5;
      int hp = (w >> 3) * 7 + t / 7 + 3; if (hp >= 56) hp -= 56;
      int wp = (w & 7) * 7 + t % 7 + 3;  if (wp >= 56) wp -= 56;
      src = b * 3141 + 5 + hp * 56 + wp;
    }
    const float* xr = x + (size_t)src * 128;
    v0a[rr] = xr[lane];
    v1a[rr] = xr[lane + 64];
  }
  // Phase B: reductions + stores (independent chains, pipelined)
  #pragma unroll
  for (int rr = 0; rr < 14; ++rr) {
    int row = wv + rr * 4;
    if (row < 54) {
      float v0 = v0a[rr], v1 = v1a[rr];
      float s = v0 + v1, s2 = v0 * v0 + v1 * v1;
      #pragma unroll
      for (int off = 32; off > 0; off >>= 1) {
        s  += __shfl_xor(s,  off);
        s2 += __shfl_xor(s2, off);
      }
      float mu = s * (1.f / 128.f);
      float var = s2 * (1.f / 128.f) - mu * mu;
      float rs = rsqrtf(var + 1e-5f);
      float y0 = (v0 - mu) * rs * n1g[lane]      + n1b[lane];
      float y1 = (v1 - mu) * rs * n1g[lane + 64] + n1b[lane + 64];
      int f = (row & 15) >> 1;
      int ca = lane, cb = lane + 64;
      xn[row * 128 + (((ca >> 3) ^ f) << 3) + (ca & 7)] = (short)f2b(y0);
      xn[row * 128 + (((cb >> 3) ^ f) << 3) + (cb & 7)] = (short)f2b(y1);
    }
  }
  // zero pad rows 54..63 (QKV A-frags read them; K/V pads masked by bias)
  for (int idx = tid; idx < 1280; idx += 256) xn[54 * 128 + idx] = 0;
  __syncthreads();

  // ================= A-fragments to registers (xn dies after) =========
  bf16x8 af[4][4];
  #pragma unroll
  for (int ks = 0; ks < 4; ++ks)
    #pragma unroll
    for (int mi = 0; mi < 4; ++mi) {
      int row = mi * 16 + c;
      af[ks][mi] = *(const bf16x8*)(xn + row * 128 +
                    (((ks * 4 + g) ^ ((row & 15) >> 1)) << 3));
    }
  // bias-table loads hoisted: latency hides under QKV MFMAs
  const unsigned short* bt = (const unsigned short*)bias_tab + ((size_t)(w * 4 + wv) << 12);
  u16x4 bb[4][4];
  #pragma unroll
  for (int ni = 0; ni < 4; ++ni)
    #pragma unroll
    for (int mi = 0; mi < 4; ++mi)
      bb[ni][mi] = *(const u16x4*)(bt + (ni * 16 + c) * 64 + mi * 16 + g * 4);
  __syncthreads();   // xn dead; QL (full 48KB) may now be written

  // ================= QKV GEMM, per-head, transposed stores ============
  {
    #pragma unroll
    for (int t = 0; t < 6; ++t) {
      int m = t >> 1;                 // 0=Q, 1=K, 2=V
      int chb = (t & 1) * 16;         // channel base within head
      int n0 = m * 128 + wv * 32 + chb;
      bf16x8 bfr[4];
      #pragma unroll
      for (int ks = 0; ks < 4; ++ks)
        bfr[ks] = *(const bf16x8*)(w_qkv + (size_t)(n0 + c) * 128 + ks * 32 + g * 8);
      f32x4 acct[4] = {};
      __builtin_amdgcn_s_setprio(1);
      #pragma unroll
      for (int ks = 0; ks < 4; ++ks)
        #pragma unroll
        for (int mi = 0; mi < 4; ++mi)
          acct[mi] = __builtin_amdgcn_mfma_f32_16x16x32_bf16(
              bfr[ks], af[ks][mi], acct[mi], 0, 0, 0);   // D[ch][tok]
      __builtin_amdgcn_s_setprio(0);
      f32x4 bq4 = *(const f32x4*)(qkv_b + n0 + g * 4);
      int cpart = (chb >> 3) + (g >> 1);
      #pragma unroll
      for (int mi = 0; mi < 4; ++mi) {
        int tok = mi * 16 + c;
        int swz = (m == 2) ? ((tok >> 3) & 3) : ((tok >> 1) & 3);
        u16x4 pw;
        #pragma unroll
        for (int r = 0; r < 4; ++r) pw[r] = f2b(acct[mi][r] + bq4[r]);
        *(u16x4*)(Lh + m * 2048 + tok * 32 + ((cpart ^ swz) << 3) + (g & 1) * 4) = pw;
      }
    }
  }

  // ================= attention (wave wv = head wv, barrier-free) ======
  {
    const int h = wv;
    bf16x8 kf[4], bq[4];
    #pragma unroll
    for (int mi = 0; mi < 4; ++mi) {
      int tok = mi * 16 + c;
      kf[mi] = *(const bf16x8*)(Lh + 2048 + tok * 32 + ((g ^ ((tok >> 1) & 3)) << 3));
    }
    #pragma unroll
    for (int ni = 0; ni < 4; ++ni) {
      int q = ni * 16 + c;
      bq[ni] = *(const bf16x8*)(Lh + q * 32 + ((g ^ ((q >> 1) & 3)) << 3));
    }
    f32x4 acc[4][4] = {};
    __builtin_amdgcn_s_setprio(1);
    #pragma unroll
    for (int mi = 0; mi < 4; ++mi)
      #pragma unroll
      for (int ni = 0; ni < 4; ++ni)
        acc[mi][ni] = __builtin_amdgcn_mfma_f32_16x16x32_bf16(kf[mi], bq[ni], acc[mi][ni], 0, 0, 0);
    __builtin_amdgcn_s_setprio(0);

    const float SC = 0.17677669529663689f * 1.44269504088896f;
    #pragma unroll
    for (int ni = 0; ni < 4; ++ni)
      #pragma unroll
      for (int mi = 0; mi < 4; ++mi)
        #pragma unroll
        for (int r = 0; r < 4; ++r)
          acc[mi][ni][r] = acc[mi][ni][r] * SC + bf2f(bb[ni][mi][r]);

    #pragma unroll
    for (int ni = 0; ni < 4; ++ni) {
      float m2 = -3.0e38f;
      #pragma unroll
      for (int mi = 0; mi < 4; ++mi)
        #pragma unroll
        for (int r = 0; r < 4; ++r)
          m2 = fmaxf(m2, acc[mi][ni][r]);
      m2 = fmaxf(m2, __shfl_xor(m2, 16, 64));
      m2 = fmaxf(m2, __shfl_xor(m2, 32, 64));
      float sm = 0.f;
      #pragma unroll
      for (int mi = 0; mi < 4; ++mi)
        #pragma unroll
        for (int r = 0; r < 4; ++r) {
          float p = exp2f(acc[mi][ni][r] - m2);
          acc[mi][ni][r] = p;
          sm += p;
        }
      sm += __shfl_xor(sm, 16, 64);
      sm += __shfl_xor(sm, 32, 64);
      float inv = 1.0f / sm;
      int q = ni * 16 + c;
      #pragma unroll
      for (int mi = 0; mi < 4; ++mi) {
        u16x4 pw;
        #pragma unroll
        for (int r = 0; r < 4; ++r) pw[r] = f2b(acc[mi][ni][r] * inv);
        int chp = (mi * 2 + (g >> 1)) ^ (q & 7);
        *(u16x4*)(Lh + q * 64 + chp * 8 + (g & 1) * 4) = pw;
      }
    }

    // PV with swapped operands: acc2[di][qi] = D[d][q]
    f32x4 acc2[2][4] = {};
    #pragma unroll
    for (int ks = 0; ks < 2; ++ks) {
      bf16x8 pa[4];
      #pragma unroll
      for (int qi = 0; qi < 4; ++qi) {
        int q = qi * 16 + c;
        int chk = (ks * 4 + g) ^ (q & 7);
        pa[qi] = *(const bf16x8*)(Lh + q * 64 + chk * 8);
      }
      bf16x8 vb[2];
      #pragma unroll
      for (int di = 0; di < 2; ++di) {
        #pragma unroll
        for (int j = 0; j < 8; ++j) {
          int k = ks * 32 + g * 8 + j;
          int chv = ((di * 2 + (c >> 3)) ^ g);
          vb[di][j] = Lh[4096 + k * 32 + chv * 8 + (c & 7)];
        }
      }
      __builtin_amdgcn_s_setprio(1);
      #pragma unroll
      for (int qi = 0; qi < 4; ++qi)
        #pragma unroll
        for (int di = 0; di < 2; ++di)
          acc2[di][qi] = __builtin_amdgcn_mfma_f32_16x16x32_bf16(vb[di], pa[qi], acc2[di][qi], 0, 0, 0);
      __builtin_amdgcn_s_setprio(0);
    }

    __syncthreads();   // all waves done with Q/K/V/Ps -> ao overlay safe
    // ao write: u16x4 of 4 consecutive channels per token
    #pragma unroll
    for (int di = 0; di < 2; ++di) {
      int chunk = h * 4 + di * 2 + (g >> 1);
      #pragma unroll
      for (int qi = 0; qi < 4; ++qi) {
        int tok = qi * 16 + c;
        u16x4 pw;
        #pragma unroll
        for (int r = 0; r < 4; ++r) pw[r] = f2b(acc2[di][qi][r]);
        *(u16x4*)(xn + tok * 128 + ((chunk ^ (c >> 1)) << 3) + (g & 1) * 4) = pw;
      }
    }
  }
  __syncthreads();

  // ================= proj GEMM + scatter epilogue =====================
  {
    f32x4 accp[4][2] = {};
    #pragma unroll
    for (int ks = 0; ks < 4; ++ks) {
      bf16x8 afp[4];
      #pragma unroll
      for (int mi = 0; mi < 4; ++mi) {
        int row = mi * 16 + c;
        afp[mi] = *(const bf16x8*)(xn + row * 128 +
                   (((ks * 4 + g) ^ ((row & 15) >> 1)) << 3));
      }
      bf16x8 wfp[2];
      #pragma unroll
      for (int ni = 0; ni < 2; ++ni)
        wfp[ni] = *(const bf16x8*)(w_prj +
            (size_t)(wv * 32 + ni * 16 + c) * 128 + ks * 32 + g * 8);
      #pragma unroll
      for (int mi = 0; mi < 4; ++mi)
        #pragma unroll
        for (int ni = 0; ni < 2; ++ni)
          accp[mi][ni] = __builtin_amdgcn_mfma_f32_16x16x32_bf16(
              afp[mi], wfp[ni], accp[mi][ni], 0, 0, 0);
    }
    float pb[2];
    pb[0] = proj_b[wv * 32 + c];
    pb[1] = proj_b[wv * 32 + 16 + c];
    #pragma unroll
    for (int mi = 0; mi < 4; ++mi) {
      #pragma unroll
      for (int r = 0; r < 4; ++r) {
        int tok = mi * 16 + g * 4 + r;
        if (tok < 54) {
          if (tok < 5) {
            #pragma unroll
            for (int ni = 0; ni < 2; ++ni) {
              int gcol = wv * 32 + ni * 16 + c;
              pbuf[((size_t)gi * 5 + tok) * 128 + gcol] = accp[mi][ni][r] + pb[ni];
            }
          } else {
            int b = gi >> 6, tt = tok - 5;
            int rr2 = (w >> 3) * 7 + tt / 7 + 3; if (rr2 >= 56) rr2 -= 56;
            int cc = (w & 7) * 7 + tt % 7 + 3;   if (cc >= 56) cc -= 56;
            size_t ob = ((size_t)b * 3141 + 5 + rr2 * 56 + cc) * 128;
            #pragma unroll
            for (int ni = 0; ni < 2; ++ni) {
              int gcol = wv * 32 + ni * 16 + c;
              out[ob + gcol] = x[ob + gcol] + accp[mi][ni][r] + pb[ni];
            }
          }
        }
      }
    }
  }
}

// ---------------------------------------------------------------------------
// Prompt mean over windows + residual
// ---------------------------------------------------------------------------
__global__ __launch_bounds__(128) void prompt_reduce(const float* __restrict__ x,
    const float* __restrict__ pbuf, float* __restrict__ out)
{
  int bp = blockIdx.x;
  int b = bp / 5, p = bp % 5;
  int c = threadIdx.x;
  float s = 0.f;
  for (int w = 0; w < 64; ++w)
    s += pbuf[((size_t)(w * 64 + b) * 5 + p) * 128 + c];
  size_t oidx = ((size_t)b * 3141 + p) * 128 + c;
  out[oidx] = x[oidx] + s * (1.f / 64.f);
}

// ---------------------------------------------------------------------------
// MLP helpers. fc1 uses swapped-operand MFMA -> packed u16x4 h-writes.
// ---------------------------------------------------------------------------
__device__ __forceinline__ void mlp_fc1(const short* __restrict__ xn,
    short* __restrict__ dst, const __hip_bfloat16* __restrict__ w1t,
    const float* __restrict__ b1, int s, int wv, int c, int g)
{
  bf16x8 wf[4][2];
  #pragma unroll
  for (int ks = 0; ks < 4; ++ks)
    #pragma unroll
    for (int ni = 0; ni < 2; ++ni)
      wf[ks][ni] = *(const bf16x8*)(w1t +
          (size_t)(s * 128 + wv * 32 + ni * 16 + c) * 128 + ks * 32 + g * 8);
  f32x4 acc1[2][4] = {};
  #pragma unroll
  for (int ks = 0; ks < 4; ++ks) {
    bf16x8 af[4];
    #pragma unroll
    for (int mi = 0; mi < 4; ++mi) {
      int row = mi * 16 + c;
      af[mi] = *(const bf16x8*)(xn + row * 128 +
                                (((ks * 4 + g) ^ ((row & 15) >> 1)) << 3));
    }
    #pragma unroll
    for (int mi = 0; mi < 4; ++mi)
      #pragma unroll
      for (int ni = 0; ni < 2; ++ni)
        acc1[ni][mi] = __builtin_amdgcn_mfma_f32_16x16x32_bf16(
            wf[ks][ni], af[mi], acc1[ni][mi], 0, 0, 0);   // D[hcol][tok]
  }
  #pragma unroll
  for (int ni = 0; ni < 2; ++ni) {
    f32x4 b1v = *(const f32x4*)(b1 + s * 128 + wv * 32 + ni * 16 + g * 4);
    int chunk = wv * 4 + ni * 2 + (g >> 1);
    #pragma unroll
    for (int mi = 0; mi < 4; ++mi) {
      int tok = mi * 16 + c;
      u16x4 pw;
      #pragma unroll
      for (int r = 0; r < 4; ++r) {
        float t = acc1[ni][mi][r] + b1v[r];
        float u = t * (0.7978845608028654f + 0.0356774081f * t * t);
        float e = exp2f(-2.8853900817779268f * u);
        t = t * __builtin_amdgcn_rcpf(1.0f + e);
        pw[r] = f2b(t);
      }
      *(u16x4*)(dst + tok * 128 + ((chunk ^ (c >> 1)) << 3) + (g & 1) * 4) = pw;
    }
  }
}

__device__ __forceinline__ void mlp_fc2(const short* __restrict__ hsrc,
    const __hip_bfloat16* __restrict__ w2t, f32x4 (&acc2)[4][2],
    int s, int wv, int c, int g)
{
  bf16x8 wf[4][2];
  #pragma unroll
  for (int ks = 0; ks < 4; ++ks)
    #pragma unroll
    for (int ni = 0; ni < 2; ++ni)
      wf[ks][ni] = *(const bf16x8*)(w2t +
          (size_t)(wv * 32 + ni * 16 + c) * 512 + s * 128 + ks * 32 + g * 8);
  #pragma unroll
  for (int ks = 0; ks < 4; ++ks) {
    bf16x8 af[4];
    #pragma unroll
    for (int mi = 0; mi < 4; ++mi) {
      int row = mi * 16 + c;
      af[mi] = *(const bf16x8*)(hsrc + row * 128 +
                                (((ks * 4 + g) ^ ((row & 15) >> 1)) << 3));
    }
    #pragma unroll
    for (int mi = 0; mi < 4; ++mi)
      #pragma unroll
      for (int ni = 0; ni < 2; ++ni)
        acc2[mi][ni] = __builtin_amdgcn_mfma_f32_16x16x32_bf16(
            af[mi], wf[ks][ni], acc2[mi][ni], 0, 0, 0);
  }
}

// ---------------------------------------------------------------------------
// Fused MLP: pipelined strips, dbuf h, 48KB LDS. LN2 loads batched.
// ---------------------------------------------------------------------------
__global__ __launch_bounds__(256, 3) void mlp_fused(
    const float* __restrict__ xin,
    const float* __restrict__ gamma, const float* __restrict__ beta,
    const __hip_bfloat16* __restrict__ w1t, const float* __restrict__ b1,
    const __hip_bfloat16* __restrict__ w2t, const float* __restrict__ b2,
    float* __restrict__ outp)
{
  __shared__ short xn[8192];
  __shared__ short hb[2][8192];
  const int tid = threadIdx.x;
  const int wv = tid >> 6, lane = tid & 63;
  const int c = lane & 15, g = lane >> 4;
  const int r0 = blockIdx.x * 64;

  float v0a[16], v1a[16];
  #pragma unroll
  for (int rr = 0; rr < 16; ++rr) {
    int row = wv * 16 + rr;
    const float* xr = xin + (size_t)(r0 + row) * 128;
    v0a[rr] = xr[lane];
    v1a[rr] = xr[lane + 64];
  }
  #pragma unroll
  for (int rr = 0; rr < 16; ++rr) {
    int row = wv * 16 + rr;
    float v0 = v0a[rr], v1 = v1a[rr];
    float s = v0 + v1, s2 = v0 * v0 + v1 * v1;
    #pragma unroll
    for (int off = 32; off > 0; off >>= 1) {
      s  += __shfl_xor(s,  off);
      s2 += __shfl_xor(s2, off);
    }
    float mu = s * (1.f / 128.f);
    float var = s2 * (1.f / 128.f) - mu * mu;
    float rs = rsqrtf(var + 1e-5f);
    float y0 = (v0 - mu) * rs * gamma[lane]      + beta[lane];
    float y1 = (v1 - mu) * rs * gamma[lane + 64] + beta[lane + 64];
    int f = (row & 15) >> 1;
    int ca = lane, cb = lane + 64;
    xn[row * 128 + (((ca >> 3) ^ f) << 3) + (ca & 7)] = (short)f2b(y0);
    xn[row * 128 + (((cb >> 3) ^ f) << 3) + (cb & 7)] = (short)f2b(y1);
  }
  __syncthreads();

  mlp_fc1(xn, hb[0], w1t, b1, 0, wv, c, g);
  __syncthreads();

  f32x4 acc2[4][2] = {};
  #pragma unroll
  for (int s = 0; s < 4; ++s) {
    if (s < 3) mlp_fc1(xn, hb[(s + 1) & 1], w1t, b1, s + 1, wv, c, g);
    mlp_fc2(hb[s & 1], w2t, acc2, s, wv, c, g);
    if (s < 3) __syncthreads();
  }

  #pragma unroll
  for (int mi = 0; mi < 4; ++mi) {
    #pragma unroll
    for (int r = 0; r < 4; ++r) {
      int row = r0 + mi * 16 + g * 4 + r;
      #pragma unroll
      for (int ni = 0; ni < 2; ++ni) {
        int col = wv * 32 + ni * 16 + c;
        size_t o = (size_t)row * 128 + col;
        outp[o] = acc2[mi][ni][r] + b2[col] + xin[o];
      }
    }
  }
}

// ---------------------------------------------------------------------------
// Launch
// ---------------------------------------------------------------------------
extern "C" void kernel_launch(void* const* d_in, const int* in_sizes, int n_in,
                              void* d_out, int out_size, void* d_ws, size_t ws_size,
                              hipStream_t stream) {
  const float* x      = (const float*)d_in[0];
  const float* n1g    = (const float*)d_in[1];
  const float* n1b    = (const float*)d_in[2];
  const float* qkv_w  = (const float*)d_in[3];
  const float* qkv_b  = (const float*)d_in[4];
  const float* proj_w = (const float*)d_in[5];
  const float* proj_b = (const float*)d_in[6];
  const float* rpb    = (const float*)d_in[7];
  const float* n2g    = (const float*)d_in[8];
  const float* n2b    = (const float*)d_in[9];
  const float* fc1w   = (const float*)d_in[10];
  const float* fc1b   = (const float*)d_in[11];
  const float* fc2w   = (const float*)d_in[12];
  const float* fc2b   = (const float*)d_in[13];
  float* out = (float*)d_out;
  char* ws = (char*)d_ws;

  __hip_bfloat16* wbuf = (__hip_bfloat16*)ws;
  __hip_bfloat16* w_qkv = wbuf;                 // [384][128]
  __hip_bfloat16* w_prj = wbuf + 49152;         // [128][128]
  __hip_bfloat16* w_fc1 = wbuf + 65536;         // [512][128]
  __hip_bfloat16* w_fc2 = wbuf + 131072;        // [128][512]
  __hip_bfloat16* bias_tab = (__hip_bfloat16*)(ws + 393216);
  float* pbuf = (float*)(ws + 2490368);         // 4096*5*128 f32 = 10.5 MB

  hipLaunchKernelGGL(convert_wt, dim3(192), dim3(256), 0, stream, qkv_w, w_qkv, 128, 384);
  hipLaunchKernelGGL(convert_wt, dim3(64),  dim3(256), 0, stream, proj_w, w_prj, 128, 128);
  hipLaunchKernelGGL(convert_wt, dim3(256), dim3(256), 0, stream, fc1w,  w_fc1, 128, 512);
  hipLaunchKernelGGL(convert_wt, dim3(256), dim3(256), 0, stream, fc2w,  w_fc2, 512, 128);
  hipLaunchKernelGGL(bias_gen, dim3(256), dim3(256), 0, stream, rpb, bias_tab);

  // Phase 1: fully fused (no intermediate HBM traffic)
  hipLaunchKernelGGL(phase1_fused, dim3(4096), dim3(256), 0, stream,
                     x, n1g, n1b, w_qkv, qkv_b, w_prj, proj_b, bias_tab, out, pbuf);
  hipLaunchKernelGGL(prompt_reduce, dim3(320), dim3(128), 0, stream, x, pbuf, out);

  // Phase 2: fused MLP (in-place on out), 201024 = 3141*64 rows
  hipLaunchKernelGGL(mlp_fused, dim3(3141), dim3(256), 0, stream,
                     out, n2g, n2b, w_fc1, fc1b, w_fc2, fc2b, out);
  (void)in_sizes; (void)n_in; (void)out_size; (void)ws_size;
}